// Round 12
// baseline (149.181 us; speedup 1.0000x reference)
//
#include <hip/hip_runtime.h>

// MHA forward: B=2, S=2048, D=1024, H=16, DK=64. fp32 in/out, bf16 MFMA compute.
// R12: rebalanced 32x32 attention (GEMMs unchanged from R10/R11).
//  R11 regression root-cause: tile->wave-pair assignment serialized tB+1 units
//  on half the SIMDs (pred 1.5x = measured 1.47x). Fix: each wave owns one
//  A-cgroup AND one B-cgroup with complementary kv spans -> exactly 33
//  C32-units per wave, every wave, every block. Block p covers 4 q-tiles
//  {p, p+8, 31-p, 23-p}; 4 q-tiles share each staged KV tile (fetch halves).

#define S_LEN 2048
#define NHEAD 16
#define DMODEL 1024
#define DKH 64
#define LDA 72   // K/V LDS row stride (bf16): 144 B, 16B-aligned

typedef unsigned short u16;
typedef unsigned int u32;
typedef __attribute__((ext_vector_type(8))) short short8;
typedef __attribute__((ext_vector_type(8))) __bf16 bf16x8;
typedef __attribute__((ext_vector_type(4))) float f32x4;
typedef __attribute__((ext_vector_type(16))) float f32x16;
typedef __attribute__((ext_vector_type(4))) unsigned int u32x4;

__device__ inline u16 f2bf(float f) {
  return __builtin_bit_cast(u16, (__bf16)f);   // v_cvt RNE
}
__device__ inline u32 pk2(float a, float b) {
  return (u32)f2bf(a) | ((u32)f2bf(b) << 16);
}

__device__ inline f32x4 mfma16x16(bf16x8 a, bf16x8 b, f32x4 c) {
  return __builtin_amdgcn_mfma_f32_16x16x32_bf16(a, b, c, 0, 0, 0);
}
__device__ inline f32x16 mfma32(bf16x8 a, bf16x8 b, f32x16 c) {
  return __builtin_amdgcn_mfma_f32_32x32x16_bf16(a, b, c, 0, 0, 0);
}

__device__ inline short8 pack8(float4 a, float4 b) {
  short8 r;
  r[0] = (short)f2bf(a.x); r[1] = (short)f2bf(a.y);
  r[2] = (short)f2bf(a.z); r[3] = (short)f2bf(a.w);
  r[4] = (short)f2bf(b.x); r[5] = (short)f2bf(b.y);
  r[6] = (short)f2bf(b.z); r[7] = (short)f2bf(b.w);
  return r;
}

typedef const __attribute__((address_space(1))) unsigned GU32;
typedef __attribute__((address_space(3))) unsigned LU32;
__device__ inline void gl2lds16(const void* g, void* l) {
  __builtin_amdgcn_global_load_lds((GU32*)g, (LU32*)l, 16, 0, 0);
}

// swizzled elem-offset into a [rows][64] bf16 tile; col8 = 16B-slot index 0..7
#define SWZ(row, col8) (((row) * 8 + ((col8) ^ ((row) & 7))) * 8)

// ---------- f32 -> bf16 conversion: 4 weights (1M) + q,k,v (4M each) ----------
__global__ __launch_bounds__(256)
void conv_bf16(const float* __restrict__ w0, const float* __restrict__ w1,
               const float* __restrict__ w2, const float* __restrict__ w3,
               const float* __restrict__ aq, const float* __restrict__ ak,
               const float* __restrict__ av,
               u16* __restrict__ o0, u16* __restrict__ o1,
               u16* __restrict__ o2, u16* __restrict__ o3,
               u16* __restrict__ oq, u16* __restrict__ ok, u16* __restrict__ ov)
{
  const int y = blockIdx.y;
  const float* s; u16* d; int n;
  switch (y) {
    case 0: s = w0; d = o0; n = 1 << 20; break;
    case 1: s = w1; d = o1; n = 1 << 20; break;
    case 2: s = w2; d = o2; n = 1 << 20; break;
    case 3: s = w3; d = o3; n = 1 << 20; break;
    case 4: s = aq; d = oq; n = 1 << 22; break;
    case 5: s = ak; d = ok; n = 1 << 22; break;
    default: s = av; d = ov; n = 1 << 22; break;
  }
  const int i = (blockIdx.x * 256 + threadIdx.x) * 8;
  if (i >= n) return;
  float4 a = *(const float4*)&s[i];
  float4 b = *(const float4*)&s[i + 4];
  *(short8*)&d[i] = pack8(a, b);
}

// ---------- weight-only conversion (fallback tier) ----------
__global__ __launch_bounds__(256)
void conv_w(const float* __restrict__ w0, const float* __restrict__ w1,
            const float* __restrict__ w2, const float* __restrict__ w3,
            u16* __restrict__ o0, u16* __restrict__ o1,
            u16* __restrict__ o2, u16* __restrict__ o3)
{
  const int z = blockIdx.y;
  const float* s = z == 0 ? w0 : z == 1 ? w1 : z == 2 ? w2 : w3;
  u16* d = z == 0 ? o0 : z == 1 ? o1 : z == 2 ? o2 : o3;
  const int i = (blockIdx.x * 256 + threadIdx.x) * 8;
  float4 a = *(const float4*)&s[i];
  float4 b = *(const float4*)&s[i + 4];
  *(short8*)&d[i] = pack8(a, b);
}

// ---------- batched projection GEMMs, all-bf16, dbuf gl_lds ----------
__global__ __launch_bounds__(256)
void proj_gemm_bf16(const u16* __restrict__ Aqb, const u16* __restrict__ Akb,
                    const u16* __restrict__ Avb,
                    const u16* __restrict__ Bq, const u16* __restrict__ Bk,
                    const u16* __restrict__ Bv,
                    const float* __restrict__ cq, const float* __restrict__ ck,
                    const float* __restrict__ cv,
                    u16* __restrict__ Oq, u16* __restrict__ Ok, u16* __restrict__ Ov)
{
  __shared__ u16 SM[4 * 8192];               // [A0][A1][B0][B1] = 64 KB

  const int hw = blockIdx.x + (blockIdx.y << 3) + (blockIdx.z << 8);  // 0..767
  const int xcd = hw & 7, sq = hw >> 3;
  const int pan = sq % 12, xb = sq / 12;
  const int p = pan * 8 + xcd;
  const int zz = p >> 5, py = p & 31;

  const u16* Ab = zz == 0 ? Aqb : zz == 1 ? Akb : Avb;
  const u16* Wb = zz == 0 ? Bq : zz == 1 ? Bk : Bv;
  const float* bias = zz == 0 ? cq : zz == 1 ? ck : cv;

  const int t = threadIdx.x;
  const int lane = t & 63;
  const int wv = t >> 6;
  const int wm = wv >> 1, wn = wv & 1;
  const int g = lane >> 4, lr = lane & 15;
  const int bm = py << 7, bn = xb << 7;
  const int K = DMODEL;

  auto STAGE = [&](int buf, int kt) {
    const int k0 = kt << 6;
    u16* Asb = SM + buf * 8192;
    u16* Bsb = SM + 16384 + buf * 8192;
#pragma unroll
    for (int i = 0; i < 4; ++i) {
      int c = t + (i << 8);
      int row = c >> 3, col8 = c & 7;
      int c8s = col8 ^ (row & 7);
      gl2lds16(&Ab[(size_t)(bm + row) * K + k0 + c8s * 8], &Asb[c * 8]);
      gl2lds16(&Wb[(size_t)(bn + row) * K + k0 + c8s * 8], &Bsb[c * 8]);
    }
  };

  f32x4 acc[4][4] = {};
  STAGE(0, 0);
  __syncthreads();
  for (int kt = 0; kt < 16; ++kt) {
    const int cur = kt & 1;
    if (kt + 1 < 16) STAGE(cur ^ 1, kt + 1);   // issue-early; drained by barrier
    u16* Asb = SM + cur * 8192;
    u16* Bsb = SM + 16384 + cur * 8192;
    bf16x8 af[2][4], bf[2][4];
#pragma unroll
    for (int kc = 0; kc < 2; ++kc)
#pragma unroll
      for (int f = 0; f < 4; ++f) {
        af[kc][f] = *(const bf16x8*)&Asb[SWZ(wm * 64 + f * 16 + lr, kc * 4 + g)];
        bf[kc][f] = *(const bf16x8*)&Bsb[SWZ(wn * 64 + f * 16 + lr, kc * 4 + g)];
      }
#pragma unroll
    for (int kc = 0; kc < 2; ++kc)
#pragma unroll
      for (int fm = 0; fm < 4; ++fm)
#pragma unroll
        for (int fn = 0; fn < 4; ++fn)
          acc[fm][fn] = mfma16x16(af[kc][fm], bf[kc][fn], acc[fm][fn]);
    __syncthreads();
  }

  if (zz == 2) {
    u16* TL = SM;
    const int b = bm >> 11, s0 = bm & (S_LEN - 1), h0 = bn >> 6;
#pragma unroll
    for (int hh = 0; hh < 2; ++hh) {
      __syncthreads();
      if (wn == hh) {
#pragma unroll
        for (int fm = 0; fm < 4; ++fm)
#pragma unroll
          for (int fn = 0; fn < 4; ++fn) {
            const int lch = fn * 16 + lr;
            const float bb = bias[bn + hh * 64 + lch];
#pragma unroll
            for (int r = 0; r < 4; ++r)
              TL[lch * 132 + wm * 64 + fm * 16 + g * 4 + r] = f2bf(acc[fm][fn][r] + bb);
          }
      }
      __syncthreads();
#pragma unroll
      for (int i = 0; i < 4; ++i) {
        int c = t + (i << 8);
        int dk = c >> 4, sc = (c & 15) << 3;
        short8 vv = *(const short8*)&TL[dk * 132 + sc];
        *(short8*)&Ov[(((size_t)(b * NHEAD + h0 + hh)) * DKH + dk) * S_LEN + s0 + sc] = vv;
      }
    }
  } else {
    u16* Out = zz == 0 ? Oq : Ok;
#pragma unroll
    for (int fm = 0; fm < 4; ++fm)
#pragma unroll
      for (int fn = 0; fn < 4; ++fn) {
        const int col = bn + wn * 64 + fn * 16 + lr;
        const int h = col >> 6, dk = col & (DKH - 1);
        const float bb = bias[col];
#pragma unroll
        for (int r = 0; r < 4; ++r) {
          const int row = bm + wm * 64 + fm * 16 + g * 4 + r;
          const int b = row >> 11, s = row & (S_LEN - 1);
          Out[(((size_t)(b * NHEAD + h)) * S_LEN + s) * DKH + dk] = f2bf(acc[fm][fn][r] + bb);
        }
      }
  }
}

// ---------- R8 proj (fp32 A reg-staged) — fallback tier ----------
__global__ __launch_bounds__(256)
void proj_gemm_f32(const float* __restrict__ Aq, const float* __restrict__ Akk,
                   const float* __restrict__ Av,
                   const u16* __restrict__ Bq, const u16* __restrict__ Bk,
                   const u16* __restrict__ Bv,
                   const float* __restrict__ cq, const float* __restrict__ ck,
                   const float* __restrict__ cv,
                   u16* __restrict__ Oq, u16* __restrict__ Ok, u16* __restrict__ Ov)
{
  __shared__ u16 SM[3 * 8192];
  u16* As = SM;
  u16* Bs0 = SM + 8192;
  u16* Bs1 = SM + 16384;

  const int hw = blockIdx.x + (blockIdx.y << 3) + (blockIdx.z << 8);
  const int xcd = hw & 7, sq = hw >> 3;
  const int pan = sq % 12, xb = sq / 12;
  const int p = pan * 8 + xcd;
  const int zz = p >> 5, py = p & 31;

  const float* Af = zz == 0 ? Aq : zz == 1 ? Akk : Av;
  const u16* Wb = zz == 0 ? Bq : zz == 1 ? Bk : Bv;
  const float* bias = zz == 0 ? cq : zz == 1 ? ck : cv;

  const int t = threadIdx.x;
  const int lane = t & 63;
  const int wv = t >> 6;
  const int wm = wv >> 1, wn = wv & 1;
  const int g = lane >> 4, lr = lane & 15;
  const int bm = py << 7, bn = xb << 7;
  const int K = DMODEL;

  float4 ax[4], ay[4];
  auto ALOAD = [&](int kt) {
    const int k0 = kt << 6;
#pragma unroll
    for (int i = 0; i < 4; ++i) {
      int c = t + (i << 8);
      int row = c >> 3, col8 = c & 7;
      const float* src = &Af[(size_t)(bm + row) * K + k0 + col8 * 8];
      ax[i] = *(const float4*)src;
      ay[i] = *(const float4*)(src + 4);
    }
  };
  auto AWRITE = [&]() {
#pragma unroll
    for (int i = 0; i < 4; ++i) {
      int c = t + (i << 8);
      int row = c >> 3, col8 = c & 7;
      *(short8*)&As[SWZ(row, col8)] = pack8(ax[i], ay[i]);
    }
  };
  auto BSTAGE = [&](u16* buf, int kt) {
    const int k0 = kt << 6;
#pragma unroll
    for (int i = 0; i < 4; ++i) {
      int c = t + (i << 8);
      int row = c >> 3, col8 = c & 7;
      int c8s = col8 ^ (row & 7);
      gl2lds16(&Wb[(size_t)(bn + row) * K + k0 + c8s * 8], &buf[c * 8]);
    }
  };

  f32x4 acc[4][4] = {};
  ALOAD(0);
  BSTAGE(Bs0, 0);
  AWRITE();
  __syncthreads();
  for (int kt = 0; kt < 16; ++kt) {
    u16* Bcur = (kt & 1) ? Bs1 : Bs0;
    u16* Bnxt = (kt & 1) ? Bs0 : Bs1;
    const bool more = (kt + 1 < 16);
    if (more) { ALOAD(kt + 1); BSTAGE(Bnxt, kt + 1); }
    bf16x8 af[2][4], bf[2][4];
#pragma unroll
    for (int kc = 0; kc < 2; ++kc)
#pragma unroll
      for (int f = 0; f < 4; ++f) {
        af[kc][f] = *(const bf16x8*)&As[SWZ(wm * 64 + f * 16 + lr, kc * 4 + g)];
        bf[kc][f] = *(const bf16x8*)&Bcur[SWZ(wn * 64 + f * 16 + lr, kc * 4 + g)];
      }
#pragma unroll
    for (int kc = 0; kc < 2; ++kc)
#pragma unroll
      for (int fm = 0; fm < 4; ++fm)
#pragma unroll
        for (int fn = 0; fn < 4; ++fn)
          acc[fm][fn] = mfma16x16(af[kc][fm], bf[kc][fn], acc[fm][fn]);
    __syncthreads();
    if (more) {
      AWRITE();
      __syncthreads();
    }
  }

  if (zz == 2) {
    u16* TL = SM;
    const int b = bm >> 11, s0 = bm & (S_LEN - 1), h0 = bn >> 6;
#pragma unroll
    for (int hh = 0; hh < 2; ++hh) {
      __syncthreads();
      if (wn == hh) {
#pragma unroll
        for (int fm = 0; fm < 4; ++fm)
#pragma unroll
          for (int fn = 0; fn < 4; ++fn) {
            const int lch = fn * 16 + lr;
            const float bb = bias[bn + hh * 64 + lch];
#pragma unroll
            for (int r = 0; r < 4; ++r)
              TL[lch * 132 + wm * 64 + fm * 16 + g * 4 + r] = f2bf(acc[fm][fn][r] + bb);
          }
      }
      __syncthreads();
#pragma unroll
      for (int i = 0; i < 4; ++i) {
        int c = t + (i << 8);
        int dk = c >> 4, sc = (c & 15) << 3;
        short8 vv = *(const short8*)&TL[dk * 132 + sc];
        *(short8*)&Ov[(((size_t)(b * NHEAD + h0 + hh)) * DKH + dk) * S_LEN + s0 + sc] = vv;
      }
    }
  } else {
    u16* Out = zz == 0 ? Oq : Ok;
#pragma unroll
    for (int fm = 0; fm < 4; ++fm)
#pragma unroll
      for (int fn = 0; fn < 4; ++fn) {
        const int col = bn + wn * 64 + fn * 16 + lr;
        const int h = col >> 6, dk = col & (DKH - 1);
        const float bb = bias[col];
#pragma unroll
        for (int r = 0; r < 4; ++r) {
          const int row = bm + wm * 64 + fm * 16 + g * 4 + r;
          const int b = row >> 11, s = row & (S_LEN - 1);
          Out[(((size_t)(b * NHEAD + h)) * S_LEN + s) * DKH + dk] = f2bf(acc[fm][fn][r] + bb);
        }
      }
  }
}

// ---------- O-projection: Ao(head-split bf16) @ Wo^T + bo -> f32 out ----------
__global__ __launch_bounds__(256)
void out_gemm(const u16* __restrict__ Ao, const u16* __restrict__ Wb,
              const float* __restrict__ bias, float* __restrict__ Out)
{
  __shared__ u16 SM[4 * 8192];
  const int hw = blockIdx.x + (blockIdx.y << 3);
  const int xcd = hw & 7, sq = hw >> 3;
  const int pan = sq & 3, xb = sq >> 2;
  const int prow = pan * 8 + xcd;

  const int t = threadIdx.x;
  const int lane = t & 63;
  const int wv = t >> 6;
  const int wm = wv >> 1, wn = wv & 1;
  const int g = lane >> 4, lr = lane & 15;
  const int bm = prow << 7, bn = xb << 7;
  const int K = DMODEL;

  auto STAGE = [&](int buf, int kt) {
    const int k0 = kt << 6;
    u16* Asb = SM + buf * 8192;
    u16* Bsb = SM + 16384 + buf * 8192;
#pragma unroll
    for (int i = 0; i < 4; ++i) {
      int c = t + (i << 8);
      int row = c >> 3, col8 = c & 7;
      int c8s = col8 ^ (row & 7);
      int grow = bm + row;
      int b = grow >> 11, s = grow & (S_LEN - 1);
      int k = k0 + c8s * 8;
      int h = k >> 6, dk = k & (DKH - 1);
      gl2lds16(&Ao[(((size_t)(b * NHEAD + h)) * S_LEN + s) * DKH + dk], &Asb[c * 8]);
      gl2lds16(&Wb[(size_t)(bn + row) * K + k0 + c8s * 8], &Bsb[c * 8]);
    }
  };

  f32x4 acc[4][4] = {};
  STAGE(0, 0);
  __syncthreads();
  for (int kt = 0; kt < 16; ++kt) {
    const int cur = kt & 1;
    if (kt + 1 < 16) STAGE(cur ^ 1, kt + 1);
    u16* Asb = SM + cur * 8192;
    u16* Bsb = SM + 16384 + cur * 8192;
    bf16x8 af[2][4], bf[2][4];
#pragma unroll
    for (int kc = 0; kc < 2; ++kc)
#pragma unroll
      for (int f = 0; f < 4; ++f) {
        af[kc][f] = *(const bf16x8*)&Asb[SWZ(wm * 64 + f * 16 + lr, kc * 4 + g)];
        bf[kc][f] = *(const bf16x8*)&Bsb[SWZ(wn * 64 + f * 16 + lr, kc * 4 + g)];
      }
#pragma unroll
    for (int kc = 0; kc < 2; ++kc)
#pragma unroll
      for (int fm = 0; fm < 4; ++fm)
#pragma unroll
        for (int fn = 0; fn < 4; ++fn)
          acc[fm][fn] = mfma16x16(af[kc][fm], bf[kc][fn], acc[fm][fn]);
    __syncthreads();
  }
#pragma unroll
  for (int fm = 0; fm < 4; ++fm)
#pragma unroll
    for (int fn = 0; fn < 4; ++fn) {
      const int col = bn + wn * 64 + fn * 16 + lr;
      const float bb = bias[col];
#pragma unroll
      for (int r = 0; r < 4; ++r) {
        const int row = bm + wm * 64 + fm * 16 + g * 4 + r;
        Out[(size_t)row * DMODEL + col] = acc[fm][fn][r] + bb;
      }
    }
}

// ---------- Flash attention, causal, 32x32 MFMA, balanced dual-tile ----------
// Block p covers q-tiles {p, p+8, 31-p, 23-p}. Wave w: A-tile p+8*(w>>1),
// B-tile 31-8*(w>>1)-p, cgroup w&1. Per-wave work = 33 C32 units (uniform).
__global__ __launch_bounds__(256, 1)
void attn_fwd(const u16* __restrict__ Qh, const u16* __restrict__ Kh,
              const u16* __restrict__ Vtg, u16* __restrict__ Ao)
{
  __shared__ u16 SM2[4][64 * LDA];   // K dbuf [0,1], V dbuf [2,3]; reused for epilogue
  const int t = threadIdx.x, lane = t & 63, w = t >> 6;
  const int l31 = lane & 31, hi = lane >> 5;
  const int bh = blockIdx.y;
  const int p = blockIdx.x;                       // 0..7
  const int grp = w >> 1, cg = w & 1;
  const int tTA = p + grp * 8;                    // A span: short
  const int tTB = 31 - grp * 8 - p;               // B span: long (complement)
  const int qgA = tTA * 64 + cg * 32 + l31;
  const int qgB = tTB * 64 + cg * 32 + l31;
  const u16* Qb = Qh + (size_t)bh * S_LEN * DKH;
  const u16* Kb = Kh + (size_t)bh * S_LEN * DKH;
  const u16* Vb = Vtg + (size_t)bh * DKH * S_LEN;

  bf16x8 qfA[4], qfB[4];
#pragma unroll
  for (int ks = 0; ks < 4; ++ks) {
    qfA[ks] = *(const bf16x8*)&Qb[(size_t)qgA * DKH + ks * 16 + 8 * hi];
    qfB[ks] = *(const bf16x8*)&Qb[(size_t)qgB * DKH + ks * 16 + 8 * hi];
  }

  f32x16 oA0 = {}, oA1 = {}, oB0 = {}, oB1 = {};
  float mA = -1e30f, lA = 0.f, mB = -1e30f, lB = 0.f;

  const int r0 = t >> 3;            // 0..31
  const int c0 = (t & 7) << 3;
  short8 kr0, kr1, vr0, vr1;

  auto LOADT = [&](int kt) {
    const int kv0 = kt << 6;
    kr0 = *(const short8*)&Kb[(size_t)(kv0 + r0) * DKH + c0];
    kr1 = *(const short8*)&Kb[(size_t)(kv0 + r0 + 32) * DKH + c0];
    vr0 = *(const short8*)&Vb[(size_t)r0 * S_LEN + kv0 + c0];
    vr1 = *(const short8*)&Vb[(size_t)(r0 + 32) * S_LEN + kv0 + c0];
  };
  auto WRITET = [&](int b) {
    *(short8*)&SM2[b][r0 * LDA + c0] = kr0;
    *(short8*)&SM2[b][(r0 + 32) * LDA + c0] = kr1;
    *(short8*)&SM2[2 + b][r0 * LDA + c0] = vr0;
    *(short8*)&SM2[2 + b][(r0 + 32) * LDA + c0] = vr1;
  };

  const float C2 = 0.18033688011f;  // 0.125 * log2(e)

  auto C32 = [&](int cur, const bf16x8* qf, f32x16& o0, f32x16& o1,
                 float& m, float& l, bool diag, int qg, int kt) {
    const u16* Kl = &SM2[cur][0];
    const u16* Vl = &SM2[2 + cur][0];
    f32x16 s0 = {}, s1 = {};
#pragma unroll
    for (int ks = 0; ks < 4; ++ks) {
      bf16x8 k0 = *(const bf16x8*)&Kl[(l31) * LDA + ks * 16 + 8 * hi];
      bf16x8 k1 = *(const bf16x8*)&Kl[(32 + l31) * LDA + ks * 16 + 8 * hi];
      s0 = mfma32(k0, qf[ks], s0);
      s1 = mfma32(k1, qf[ks], s1);
    }
    if (diag) {
      const int kv0 = kt << 6;
#pragma unroll
      for (int r = 0; r < 16; ++r) {
        const int cr = (r & 3) + 8 * (r >> 2) + 4 * hi;
        if (kv0 + cr > qg) s0[r] = -1e30f;
        if (kv0 + 32 + cr > qg) s1[r] = -1e30f;
      }
    }
    float pm = fmaxf(s0[0], s0[1]);
#pragma unroll
    for (int r = 2; r < 16; ++r) pm = fmaxf(pm, s0[r]);
#pragma unroll
    for (int r = 0; r < 16; ++r) pm = fmaxf(pm, s1[r]);
    pm = fmaxf(pm, __shfl_xor(pm, 32, 64));
    float alpha = 1.0f;
    if (!__all(pm - m <= 64.0f)) {
      const float mn = fmaxf(m, pm);
      alpha = exp2f((m - mn) * C2);
      m = mn;
#pragma unroll
      for (int r = 0; r < 16; ++r) { o0[r] *= alpha; o1[r] *= alpha; }
    }
    const float mC = m * C2;
    float rs = 0.f;
#pragma unroll
    for (int r = 0; r < 16; ++r) {
      s0[r] = exp2f(fmaf(s0[r], C2, -mC));
      s1[r] = exp2f(fmaf(s1[r], C2, -mC));
      rs += s0[r] + s1[r];
    }
    rs += __shfl_xor(rs, 32, 64);
    l = l * alpha + rs;
    bf16x8 pb[4];
#pragma unroll
    for (int s = 0; s < 4; ++s) {
      const int rb = (s & 1) * 8;
      float e0, e1, e2, e3, e4, e5, e6, e7;
      if (s >> 1) {
        e0 = s1[rb+0]; e1 = s1[rb+1]; e2 = s1[rb+2]; e3 = s1[rb+3];
        e4 = s1[rb+4]; e5 = s1[rb+5]; e6 = s1[rb+6]; e7 = s1[rb+7];
      } else {
        e0 = s0[rb+0]; e1 = s0[rb+1]; e2 = s0[rb+2]; e3 = s0[rb+3];
        e4 = s0[rb+4]; e5 = s0[rb+5]; e6 = s0[rb+6]; e7 = s0[rb+7];
      }
      u32 wlo  = pk2(e0, e1);
      u32 wlo2 = pk2(e2, e3);
      u32 whi  = pk2(e4, e5);
      u32 whi2 = pk2(e6, e7);
      u32 sA = __shfl_xor(wlo, 32, 64);
      u32 sB = __shfl_xor(wlo2, 32, 64);
      u32 sC = __shfl_xor(whi, 32, 64);
      u32 sD = __shfl_xor(whi2, 32, 64);
      u32x4 uw;
      uw[0] = hi ? sC : wlo;
      uw[1] = hi ? sD : wlo2;
      uw[2] = hi ? whi : sA;
      uw[3] = hi ? whi2 : sB;
      pb[s] = __builtin_bit_cast(bf16x8, uw);
    }
#pragma unroll
    for (int s = 0; s < 4; ++s) {
      bf16x8 v0 = *(const bf16x8*)&Vl[(l31) * LDA + s * 16 + 8 * hi];
      bf16x8 v1 = *(const bf16x8*)&Vl[(32 + l31) * LDA + s * 16 + 8 * hi];
      o0 = mfma32(v0, pb[s], o0);
      o1 = mfma32(v1, pb[s], o1);
    }
  };

  const int nt = 32 - p;             // B-long tile (31-p) + 1
  LOADT(0);
  WRITET(0);
  for (int kt = 0; kt < nt; ++kt) {
    const int cur = kt & 1;
    const bool more = (kt + 1 < nt);
    if (more) LOADT(kt + 1);
    __syncthreads();
    if (kt <= tTA) C32(cur, qfA, oA0, oA1, mA, lA, kt == tTA, qgA, kt);
    if (kt <= tTB) C32(cur, qfB, oB0, oB1, mB, lB, kt == tTB, qgB, kt);
    if (more) WRITET(cur ^ 1);
  }

  // epilogue: normalize (lane-local l), restage 4 tiles via LDS, coalesced out
  const float ilA = __builtin_amdgcn_rcpf(lA);
  const float ilB = __builtin_amdgcn_rcpf(lB);
  __syncthreads();
  u16* OsA = &SM2[0][0] + (size_t)grp * 64 * LDA;        // A1->0, A2->1
  u16* OsB = &SM2[0][0] + (size_t)(2 + grp) * 64 * LDA;  // B1->2, B2->3
  const int rl = cg * 32 + l31;
#pragma unroll
  for (int r = 0; r < 16; ++r) {
    const int cr = (r & 3) + 8 * (r >> 2) + 4 * hi;
    OsA[rl * LDA + cr] = f2bf(oA0[r] * ilA);
    OsA[rl * LDA + 32 + cr] = f2bf(oA1[r] * ilA);
    OsB[rl * LDA + cr] = f2bf(oB0[r] * ilB);
    OsB[rl * LDA + 32 + cr] = f2bf(oB1[r] * ilB);
  }
  __syncthreads();
#pragma unroll
  for (int i = 0; i < 8; ++i) {
    const int c = t + (i << 8);      // 0..2047
    const int tile = c >> 9;
    const int row = (c >> 3) & 63;
    const int c8 = (c & 7) << 3;
    const int tq = (tile == 0) ? p : (tile == 1) ? p + 8
                 : (tile == 2) ? 31 - p : 23 - p;
    *(short8*)&Ao[((size_t)bh * S_LEN + tq * 64 + row) * DKH + c8] =
        *(const short8*)(&SM2[0][0] + (size_t)tile * 64 * LDA + row * LDA + c8);
  }
}

extern "C" void kernel_launch(void* const* d_in, const int* in_sizes, int n_in,
                              void* d_out, int out_size, void* d_ws, size_t ws_size,
                              hipStream_t stream)
{
  (void)in_sizes; (void)n_in; (void)out_size;
  const float* q  = (const float*)d_in[0];
  const float* k  = (const float*)d_in[1];
  const float* v  = (const float*)d_in[2];
  const float* Wq = (const float*)d_in[4];
  const float* bq = (const float*)d_in[5];
  const float* Wk = (const float*)d_in[6];
  const float* bk = (const float*)d_in[7];
  const float* Wv = (const float*)d_in[8];
  const float* bv = (const float*)d_in[9];
  const float* Wo = (const float*)d_in[10];
  const float* bo = (const float*)d_in[11];

  char* ws = (char*)d_ws;
  const size_t MB = 1024 * 1024;

  if (ws_size >= 56 * MB) {
    u16* Wqb = (u16*)(ws);               // 2 MB each
    u16* Wkb = (u16*)(ws + 2 * MB);
    u16* Wvb = (u16*)(ws + 4 * MB);
    u16* Wob = (u16*)(ws + 6 * MB);
    u16* qb  = (u16*)(ws + 8 * MB);      // 8 MB each (bf16 activations)
    u16* kb  = (u16*)(ws + 16 * MB);
    u16* vb  = (u16*)(ws + 24 * MB);
    u16* Qh  = (u16*)(ws + 32 * MB);
    u16* Kh  = (u16*)(ws + 40 * MB);
    u16* Vt  = (u16*)(ws + 48 * MB);
    u16* Ao  = qb;                       // qb dead after proj -> alias

    conv_bf16<<<dim3(2048, 7), 256, 0, stream>>>(Wq, Wk, Wv, Wo, q, k, v,
                                                 Wqb, Wkb, Wvb, Wob, qb, kb, vb);
    proj_gemm_bf16<<<dim3(8, 32, 3), 256, 0, stream>>>(qb, kb, vb, Wqb, Wkb, Wvb,
                                                       bq, bk, bv, Qh, Kh, Vt);
    attn_fwd<<<dim3(8, 2 * NHEAD), 256, 0, stream>>>(Qh, Kh, Vt, Ao);
    out_gemm<<<dim3(8, 32), 256, 0, stream>>>(Ao, Wob, bo, (float*)d_out);
  } else {
    // R8 fallback (40 MB scratch)
    u16* Wqb = (u16*)(ws);
    u16* Wkb = (u16*)(ws + 2 * MB);
    u16* Wvb = (u16*)(ws + 4 * MB);
    u16* Wob = (u16*)(ws + 6 * MB);
    u16* Qh  = (u16*)(ws + 8 * MB);
    u16* Kh  = (u16*)(ws + 16 * MB);
    u16* Vt  = (u16*)(ws + 24 * MB);
    u16* Ao  = (u16*)(ws + 32 * MB);

    conv_w<<<dim3(512, 4), 256, 0, stream>>>(Wq, Wk, Wv, Wo, Wqb, Wkb, Wvb, Wob);
    proj_gemm_f32<<<dim3(8, 32, 3), 256, 0, stream>>>(q, k, v, Wqb, Wkb, Wvb,
                                                      bq, bk, bv, Qh, Kh, Vt);
    attn_fwd<<<dim3(8, 2 * NHEAD), 256, 0, stream>>>(Qh, Kh, Vt, Ao);
    out_gemm<<<dim3(8, 32), 256, 0, stream>>>(Ao, Wob, bo, (float*)d_out);
  }
}

// Round 13
// 124.147 us; speedup vs baseline: 1.2017x; 1.2017x over previous
//
#include <hip/hip_runtime.h>

// MHA forward: B=2, S=2048, D=1024, H=16, DK=64. fp32 in/out, bf16 MFMA compute.
// R13: revert attn to R10's proven 16x16 structure (55.4us) + in-place fixes:
//  - K/V LDS: LDT 88->64 + XOR swizzle (write slot (t&7)^(row&7), read slot
//    (kc*4+g)^(row&7)) -> b128 frag reads hit the 8-clk optimum (was ~16)
//  - exp2f/fmaf softmax (1 fma + 1 exp2 per elem; was sub+mul+exp)
//  - T5 s_setprio(1) around MFMA clusters
//  R11/R12 32x32 ports regressed (imbalance 1.47x; then 1 wave/SIMD cap).

#define S_LEN 2048
#define NHEAD 16
#define DMODEL 1024
#define DKH 64
#define LDT 88   // Ps row stride (bf16)

typedef unsigned short u16;
typedef __attribute__((ext_vector_type(4))) short short4v;
typedef __attribute__((ext_vector_type(8))) short short8;
typedef __attribute__((ext_vector_type(8))) __bf16 bf16x8;
typedef __attribute__((ext_vector_type(4))) float f32x4;

__device__ inline u16 f2bf(float f) {
  return __builtin_bit_cast(u16, (__bf16)f);   // v_cvt RNE
}

__device__ inline f32x4 mfma16x16(bf16x8 a, bf16x8 b, f32x4 c) {
  return __builtin_amdgcn_mfma_f32_16x16x32_bf16(a, b, c, 0, 0, 0);
}

__device__ inline short8 pack8(float4 a, float4 b) {
  short8 r;
  r[0] = (short)f2bf(a.x); r[1] = (short)f2bf(a.y);
  r[2] = (short)f2bf(a.z); r[3] = (short)f2bf(a.w);
  r[4] = (short)f2bf(b.x); r[5] = (short)f2bf(b.y);
  r[6] = (short)f2bf(b.z); r[7] = (short)f2bf(b.w);
  return r;
}

typedef const __attribute__((address_space(1))) unsigned GU32;
typedef __attribute__((address_space(3))) unsigned LU32;
__device__ inline void gl2lds16(const void* g, void* l) {
  __builtin_amdgcn_global_load_lds((GU32*)g, (LU32*)l, 16, 0, 0);
}

// swizzled elem-offset into a [rows][64] bf16 tile; col8 = 16B-slot index 0..7
#define SWZ(row, col8) (((row) * 8 + ((col8) ^ ((row) & 7))) * 8)

// ---------- f32 -> bf16 conversion: 4 weights (1M) + q,k,v (4M each) ----------
__global__ __launch_bounds__(256)
void conv_bf16(const float* __restrict__ w0, const float* __restrict__ w1,
               const float* __restrict__ w2, const float* __restrict__ w3,
               const float* __restrict__ aq, const float* __restrict__ ak,
               const float* __restrict__ av,
               u16* __restrict__ o0, u16* __restrict__ o1,
               u16* __restrict__ o2, u16* __restrict__ o3,
               u16* __restrict__ oq, u16* __restrict__ ok, u16* __restrict__ ov)
{
  const int y = blockIdx.y;
  const float* s; u16* d; int n;
  switch (y) {
    case 0: s = w0; d = o0; n = 1 << 20; break;
    case 1: s = w1; d = o1; n = 1 << 20; break;
    case 2: s = w2; d = o2; n = 1 << 20; break;
    case 3: s = w3; d = o3; n = 1 << 20; break;
    case 4: s = aq; d = oq; n = 1 << 22; break;
    case 5: s = ak; d = ok; n = 1 << 22; break;
    default: s = av; d = ov; n = 1 << 22; break;
  }
  const int i = (blockIdx.x * 256 + threadIdx.x) * 8;
  if (i >= n) return;
  float4 a = *(const float4*)&s[i];
  float4 b = *(const float4*)&s[i + 4];
  *(short8*)&d[i] = pack8(a, b);
}

// ---------- weight-only conversion (fallback tier) ----------
__global__ __launch_bounds__(256)
void conv_w(const float* __restrict__ w0, const float* __restrict__ w1,
            const float* __restrict__ w2, const float* __restrict__ w3,
            u16* __restrict__ o0, u16* __restrict__ o1,
            u16* __restrict__ o2, u16* __restrict__ o3)
{
  const int z = blockIdx.y;
  const float* s = z == 0 ? w0 : z == 1 ? w1 : z == 2 ? w2 : w3;
  u16* d = z == 0 ? o0 : z == 1 ? o1 : z == 2 ? o2 : o3;
  const int i = (blockIdx.x * 256 + threadIdx.x) * 8;
  float4 a = *(const float4*)&s[i];
  float4 b = *(const float4*)&s[i + 4];
  *(short8*)&d[i] = pack8(a, b);
}

// ---------- batched projection GEMMs, all-bf16, dbuf gl_lds ----------
__global__ __launch_bounds__(256)
void proj_gemm_bf16(const u16* __restrict__ Aqb, const u16* __restrict__ Akb,
                    const u16* __restrict__ Avb,
                    const u16* __restrict__ Bq, const u16* __restrict__ Bk,
                    const u16* __restrict__ Bv,
                    const float* __restrict__ cq, const float* __restrict__ ck,
                    const float* __restrict__ cv,
                    u16* __restrict__ Oq, u16* __restrict__ Ok, u16* __restrict__ Ov)
{
  __shared__ u16 SM[4 * 8192];               // [A0][A1][B0][B1] = 64 KB

  const int hw = blockIdx.x + (blockIdx.y << 3) + (blockIdx.z << 8);  // 0..767
  const int xcd = hw & 7, sq = hw >> 3;
  const int pan = sq % 12, xb = sq / 12;
  const int p = pan * 8 + xcd;
  const int zz = p >> 5, py = p & 31;

  const u16* Ab = zz == 0 ? Aqb : zz == 1 ? Akb : Avb;
  const u16* Wb = zz == 0 ? Bq : zz == 1 ? Bk : Bv;
  const float* bias = zz == 0 ? cq : zz == 1 ? ck : cv;

  const int t = threadIdx.x;
  const int lane = t & 63;
  const int wv = t >> 6;
  const int wm = wv >> 1, wn = wv & 1;
  const int g = lane >> 4, lr = lane & 15;
  const int bm = py << 7, bn = xb << 7;
  const int K = DMODEL;

  auto STAGE = [&](int buf, int kt) {
    const int k0 = kt << 6;
    u16* Asb = SM + buf * 8192;
    u16* Bsb = SM + 16384 + buf * 8192;
#pragma unroll
    for (int i = 0; i < 4; ++i) {
      int c = t + (i << 8);
      int row = c >> 3, col8 = c & 7;
      int c8s = col8 ^ (row & 7);
      gl2lds16(&Ab[(size_t)(bm + row) * K + k0 + c8s * 8], &Asb[c * 8]);
      gl2lds16(&Wb[(size_t)(bn + row) * K + k0 + c8s * 8], &Bsb[c * 8]);
    }
  };

  f32x4 acc[4][4] = {};
  STAGE(0, 0);
  __syncthreads();
  for (int kt = 0; kt < 16; ++kt) {
    const int cur = kt & 1;
    if (kt + 1 < 16) STAGE(cur ^ 1, kt + 1);   // issue-early; drained by barrier
    u16* Asb = SM + cur * 8192;
    u16* Bsb = SM + 16384 + cur * 8192;
    bf16x8 af[2][4], bf[2][4];
#pragma unroll
    for (int kc = 0; kc < 2; ++kc)
#pragma unroll
      for (int f = 0; f < 4; ++f) {
        af[kc][f] = *(const bf16x8*)&Asb[SWZ(wm * 64 + f * 16 + lr, kc * 4 + g)];
        bf[kc][f] = *(const bf16x8*)&Bsb[SWZ(wn * 64 + f * 16 + lr, kc * 4 + g)];
      }
#pragma unroll
    for (int kc = 0; kc < 2; ++kc)
#pragma unroll
      for (int fm = 0; fm < 4; ++fm)
#pragma unroll
        for (int fn = 0; fn < 4; ++fn)
          acc[fm][fn] = mfma16x16(af[kc][fm], bf[kc][fn], acc[fm][fn]);
    __syncthreads();
  }

  if (zz == 2) {
    u16* TL = SM;
    const int b = bm >> 11, s0 = bm & (S_LEN - 1), h0 = bn >> 6;
#pragma unroll
    for (int hh = 0; hh < 2; ++hh) {
      __syncthreads();
      if (wn == hh) {
#pragma unroll
        for (int fm = 0; fm < 4; ++fm)
#pragma unroll
          for (int fn = 0; fn < 4; ++fn) {
            const int lch = fn * 16 + lr;
            const float bb = bias[bn + hh * 64 + lch];
#pragma unroll
            for (int r = 0; r < 4; ++r)
              TL[lch * 132 + wm * 64 + fm * 16 + g * 4 + r] = f2bf(acc[fm][fn][r] + bb);
          }
      }
      __syncthreads();
#pragma unroll
      for (int i = 0; i < 4; ++i) {
        int c = t + (i << 8);
        int dk = c >> 4, sc = (c & 15) << 3;
        short8 vv = *(const short8*)&TL[dk * 132 + sc];
        *(short8*)&Ov[(((size_t)(b * NHEAD + h0 + hh)) * DKH + dk) * S_LEN + s0 + sc] = vv;
      }
    }
  } else {
    u16* Out = zz == 0 ? Oq : Ok;
#pragma unroll
    for (int fm = 0; fm < 4; ++fm)
#pragma unroll
      for (int fn = 0; fn < 4; ++fn) {
        const int col = bn + wn * 64 + fn * 16 + lr;
        const int h = col >> 6, dk = col & (DKH - 1);
        const float bb = bias[col];
#pragma unroll
        for (int r = 0; r < 4; ++r) {
          const int row = bm + wm * 64 + fm * 16 + g * 4 + r;
          const int b = row >> 11, s = row & (S_LEN - 1);
          Out[(((size_t)(b * NHEAD + h)) * S_LEN + s) * DKH + dk] = f2bf(acc[fm][fn][r] + bb);
        }
      }
  }
}

// ---------- R8 proj (fp32 A reg-staged) — fallback tier ----------
__global__ __launch_bounds__(256)
void proj_gemm_f32(const float* __restrict__ Aq, const float* __restrict__ Akk,
                   const float* __restrict__ Av,
                   const u16* __restrict__ Bq, const u16* __restrict__ Bk,
                   const u16* __restrict__ Bv,
                   const float* __restrict__ cq, const float* __restrict__ ck,
                   const float* __restrict__ cv,
                   u16* __restrict__ Oq, u16* __restrict__ Ok, u16* __restrict__ Ov)
{
  __shared__ u16 SM[3 * 8192];
  u16* As = SM;
  u16* Bs0 = SM + 8192;
  u16* Bs1 = SM + 16384;

  const int hw = blockIdx.x + (blockIdx.y << 3) + (blockIdx.z << 8);
  const int xcd = hw & 7, sq = hw >> 3;
  const int pan = sq % 12, xb = sq / 12;
  const int p = pan * 8 + xcd;
  const int zz = p >> 5, py = p & 31;

  const float* Af = zz == 0 ? Aq : zz == 1 ? Akk : Av;
  const u16* Wb = zz == 0 ? Bq : zz == 1 ? Bk : Bv;
  const float* bias = zz == 0 ? cq : zz == 1 ? ck : cv;

  const int t = threadIdx.x;
  const int lane = t & 63;
  const int wv = t >> 6;
  const int wm = wv >> 1, wn = wv & 1;
  const int g = lane >> 4, lr = lane & 15;
  const int bm = py << 7, bn = xb << 7;
  const int K = DMODEL;

  float4 ax[4], ay[4];
  auto ALOAD = [&](int kt) {
    const int k0 = kt << 6;
#pragma unroll
    for (int i = 0; i < 4; ++i) {
      int c = t + (i << 8);
      int row = c >> 3, col8 = c & 7;
      const float* src = &Af[(size_t)(bm + row) * K + k0 + col8 * 8];
      ax[i] = *(const float4*)src;
      ay[i] = *(const float4*)(src + 4);
    }
  };
  auto AWRITE = [&]() {
#pragma unroll
    for (int i = 0; i < 4; ++i) {
      int c = t + (i << 8);
      int row = c >> 3, col8 = c & 7;
      *(short8*)&As[SWZ(row, col8)] = pack8(ax[i], ay[i]);
    }
  };
  auto BSTAGE = [&](u16* buf, int kt) {
    const int k0 = kt << 6;
#pragma unroll
    for (int i = 0; i < 4; ++i) {
      int c = t + (i << 8);
      int row = c >> 3, col8 = c & 7;
      int c8s = col8 ^ (row & 7);
      gl2lds16(&Wb[(size_t)(bn + row) * K + k0 + c8s * 8], &buf[c * 8]);
    }
  };

  f32x4 acc[4][4] = {};
  ALOAD(0);
  BSTAGE(Bs0, 0);
  AWRITE();
  __syncthreads();
  for (int kt = 0; kt < 16; ++kt) {
    u16* Bcur = (kt & 1) ? Bs1 : Bs0;
    u16* Bnxt = (kt & 1) ? Bs0 : Bs1;
    const bool more = (kt + 1 < 16);
    if (more) { ALOAD(kt + 1); BSTAGE(Bnxt, kt + 1); }
    bf16x8 af[2][4], bf[2][4];
#pragma unroll
    for (int kc = 0; kc < 2; ++kc)
#pragma unroll
      for (int f = 0; f < 4; ++f) {
        af[kc][f] = *(const bf16x8*)&As[SWZ(wm * 64 + f * 16 + lr, kc * 4 + g)];
        bf[kc][f] = *(const bf16x8*)&Bcur[SWZ(wn * 64 + f * 16 + lr, kc * 4 + g)];
      }
#pragma unroll
    for (int kc = 0; kc < 2; ++kc)
#pragma unroll
      for (int fm = 0; fm < 4; ++fm)
#pragma unroll
        for (int fn = 0; fn < 4; ++fn)
          acc[fm][fn] = mfma16x16(af[kc][fm], bf[kc][fn], acc[fm][fn]);
    __syncthreads();
    if (more) {
      AWRITE();
      __syncthreads();
    }
  }

  if (zz == 2) {
    u16* TL = SM;
    const int b = bm >> 11, s0 = bm & (S_LEN - 1), h0 = bn >> 6;
#pragma unroll
    for (int hh = 0; hh < 2; ++hh) {
      __syncthreads();
      if (wn == hh) {
#pragma unroll
        for (int fm = 0; fm < 4; ++fm)
#pragma unroll
          for (int fn = 0; fn < 4; ++fn) {
            const int lch = fn * 16 + lr;
            const float bb = bias[bn + hh * 64 + lch];
#pragma unroll
            for (int r = 0; r < 4; ++r)
              TL[lch * 132 + wm * 64 + fm * 16 + g * 4 + r] = f2bf(acc[fm][fn][r] + bb);
          }
      }
      __syncthreads();
#pragma unroll
      for (int i = 0; i < 4; ++i) {
        int c = t + (i << 8);
        int dk = c >> 4, sc = (c & 15) << 3;
        short8 vv = *(const short8*)&TL[dk * 132 + sc];
        *(short8*)&Ov[(((size_t)(b * NHEAD + h0 + hh)) * DKH + dk) * S_LEN + s0 + sc] = vv;
      }
    }
  } else {
    u16* Out = zz == 0 ? Oq : Ok;
#pragma unroll
    for (int fm = 0; fm < 4; ++fm)
#pragma unroll
      for (int fn = 0; fn < 4; ++fn) {
        const int col = bn + wn * 64 + fn * 16 + lr;
        const int h = col >> 6, dk = col & (DKH - 1);
        const float bb = bias[col];
#pragma unroll
        for (int r = 0; r < 4; ++r) {
          const int row = bm + wm * 64 + fm * 16 + g * 4 + r;
          const int b = row >> 11, s = row & (S_LEN - 1);
          Out[(((size_t)(b * NHEAD + h)) * S_LEN + s) * DKH + dk] = f2bf(acc[fm][fn][r] + bb);
        }
      }
  }
}

// ---------- O-projection: Ao(head-split bf16) @ Wo^T + bo -> f32 out ----------
__global__ __launch_bounds__(256)
void out_gemm(const u16* __restrict__ Ao, const u16* __restrict__ Wb,
              const float* __restrict__ bias, float* __restrict__ Out)
{
  __shared__ u16 SM[4 * 8192];
  const int hw = blockIdx.x + (blockIdx.y << 3);
  const int xcd = hw & 7, sq = hw >> 3;
  const int pan = sq & 3, xb = sq >> 2;
  const int prow = pan * 8 + xcd;

  const int t = threadIdx.x;
  const int lane = t & 63;
  const int wv = t >> 6;
  const int wm = wv >> 1, wn = wv & 1;
  const int g = lane >> 4, lr = lane & 15;
  const int bm = prow << 7, bn = xb << 7;
  const int K = DMODEL;

  auto STAGE = [&](int buf, int kt) {
    const int k0 = kt << 6;
    u16* Asb = SM + buf * 8192;
    u16* Bsb = SM + 16384 + buf * 8192;
#pragma unroll
    for (int i = 0; i < 4; ++i) {
      int c = t + (i << 8);
      int row = c >> 3, col8 = c & 7;
      int c8s = col8 ^ (row & 7);
      int grow = bm + row;
      int b = grow >> 11, s = grow & (S_LEN - 1);
      int k = k0 + c8s * 8;
      int h = k >> 6, dk = k & (DKH - 1);
      gl2lds16(&Ao[(((size_t)(b * NHEAD + h)) * S_LEN + s) * DKH + dk], &Asb[c * 8]);
      gl2lds16(&Wb[(size_t)(bn + row) * K + k0 + c8s * 8], &Bsb[c * 8]);
    }
  };

  f32x4 acc[4][4] = {};
  STAGE(0, 0);
  __syncthreads();
  for (int kt = 0; kt < 16; ++kt) {
    const int cur = kt & 1;
    if (kt + 1 < 16) STAGE(cur ^ 1, kt + 1);
    u16* Asb = SM + cur * 8192;
    u16* Bsb = SM + 16384 + cur * 8192;
    bf16x8 af[2][4], bf[2][4];
#pragma unroll
    for (int kc = 0; kc < 2; ++kc)
#pragma unroll
      for (int f = 0; f < 4; ++f) {
        af[kc][f] = *(const bf16x8*)&Asb[SWZ(wm * 64 + f * 16 + lr, kc * 4 + g)];
        bf[kc][f] = *(const bf16x8*)&Bsb[SWZ(wn * 64 + f * 16 + lr, kc * 4 + g)];
      }
#pragma unroll
    for (int kc = 0; kc < 2; ++kc)
#pragma unroll
      for (int fm = 0; fm < 4; ++fm)
#pragma unroll
        for (int fn = 0; fn < 4; ++fn)
          acc[fm][fn] = mfma16x16(af[kc][fm], bf[kc][fn], acc[fm][fn]);
    __syncthreads();
  }
#pragma unroll
  for (int fm = 0; fm < 4; ++fm)
#pragma unroll
    for (int fn = 0; fn < 4; ++fn) {
      const int col = bn + wn * 64 + fn * 16 + lr;
      const float bb = bias[col];
#pragma unroll
      for (int r = 0; r < 4; ++r) {
        const int row = bm + wm * 64 + fm * 16 + g * 4 + r;
        Out[(size_t)row * DMODEL + col] = acc[fm][fn][r] + bb;
      }
    }
}

// ---------- Flash attention, causal, paired {p,31-p}, head-split Ao ----------
// R10 structure; K/V at LDT=64 + XOR swizzle; exp2 softmax; setprio MFMA.
// KSW: elem offset of 16B slot `slot` in swizzled row `row` of a [64][64] tile.
#define KSW(row, slot) (((row) << 6) + ((((slot) ^ ((row) & 7))) << 3))
__global__ __launch_bounds__(256)
void attn_fwd(const u16* __restrict__ Qh, const u16* __restrict__ Kh,
              const u16* __restrict__ Vtg, u16* __restrict__ Ao)
{
  __shared__ u16 Ks[2][64 * 64];
  __shared__ u16 Vs[2][64 * 64];
  __shared__ u16 Ps[8][16 * LDT];
  const int t = threadIdx.x, lane = t & 63, w = t >> 6;
  const int g = lane >> 4, lr = lane & 15;
  const int bh = blockIdx.y;
  const int pA = blockIdx.x;
  const int tA = pA, tB = 31 - pA;
  const u16* Qb = Qh + (size_t)bh * S_LEN * DKH;
  const u16* Kb = Kh + (size_t)bh * S_LEN * DKH;
  const u16* Vb = Vtg + (size_t)bh * DKH * S_LEN;

  bf16x8 qfA[2], qfB[2];
#pragma unroll
  for (int kc = 0; kc < 2; ++kc) {
    qfA[kc] = *(const bf16x8*)&Qb[(size_t)(tA * 64 + w * 16 + lr) * DKH + kc * 32 + g * 8];
    qfB[kc] = *(const bf16x8*)&Qb[(size_t)(tB * 64 + w * 16 + lr) * DKH + kc * 32 + g * 8];
  }

  f32x4 oA[4] = {}, oB[4] = {};
  float mA = -1e30f, lA = 0.f, mB = -1e30f, lB = 0.f;

  const int r0 = t >> 3;            // 0..31
  const int sl0 = t & 7;            // 16B slot 0..7
  short8 kr0, kr1, vr0, vr1;

  auto LOADT = [&](int kt) {
    const int kv0 = kt << 6;
    const int c0 = sl0 << 3;
    kr0 = *(const short8*)&Kb[(size_t)(kv0 + r0) * DKH + c0];
    kr1 = *(const short8*)&Kb[(size_t)(kv0 + r0 + 32) * DKH + c0];
    vr0 = *(const short8*)&Vb[(size_t)r0 * S_LEN + kv0 + c0];
    vr1 = *(const short8*)&Vb[(size_t)(r0 + 32) * S_LEN + kv0 + c0];
  };
  auto WRITET = [&](int b) {
    *(short8*)&Ks[b][KSW(r0, sl0)] = kr0;
    *(short8*)&Ks[b][KSW(r0 + 32, sl0)] = kr1;
    *(short8*)&Vs[b][KSW(r0, sl0)] = vr0;
    *(short8*)&Vs[b][KSW(r0 + 32, sl0)] = vr1;
  };

  const float C2 = 0.18033688011f;  // 0.125 * log2(e)

  auto COMPUTE = [&](int buf, const bf16x8* qf, f32x4* o, float& m, float& l,
                     int pslot, bool diag) {
    // S^T tile: S[kv][q] = mfma(K, Q). lane: kv = fk*16 + 4g + r, q = lr.
    f32x4 sf[4];
    __builtin_amdgcn_s_setprio(1);
#pragma unroll
    for (int fk = 0; fk < 4; ++fk) {
      f32x4 a = {};
#pragma unroll
      for (int kc = 0; kc < 2; ++kc) {
        bf16x8 kf = *(const bf16x8*)&Ks[buf][KSW(fk * 16 + lr, kc * 4 + g)];
        a = mfma16x16(kf, qf[kc], a);
      }
      sf[fk] = a;
    }
    __builtin_amdgcn_s_setprio(0);
    if (diag) {
#pragma unroll
      for (int fk = 0; fk < 4; ++fk)
#pragma unroll
        for (int r = 0; r < 4; ++r)
          if (fk * 16 + 4 * g + r > w * 16 + lr) sf[fk][r] = -1e30f;
    }
    float pm = fmaxf(fmaxf(sf[0][0], sf[0][1]), fmaxf(sf[0][2], sf[0][3]));
#pragma unroll
    for (int fk = 1; fk < 4; ++fk)
      pm = fmaxf(pm, fmaxf(fmaxf(sf[fk][0], sf[fk][1]), fmaxf(sf[fk][2], sf[fk][3])));
    pm = fmaxf(pm, __shfl_xor(pm, 16, 64));
    pm = fmaxf(pm, __shfl_xor(pm, 32, 64));
    float alpha = 1.0f;
    if (!__all(pm - m <= 64.0f)) {            // defer-rescale (raw thr 64 = 8/8)
      float mn = fmaxf(m, pm);
      alpha = exp2f((m - mn) * C2);
      m = mn;
#pragma unroll
      for (int r = 0; r < 4; ++r) {
        float ar = __shfl(alpha, 4 * g + r, 64);
#pragma unroll
        for (int d = 0; d < 4; ++d) o[d][r] *= ar;
      }
    }
    const float mC = m * C2;
    float rs = 0.f;
#pragma unroll
    for (int fk = 0; fk < 4; ++fk) {
      float p0 = exp2f(fmaf(sf[fk][0], C2, -mC));
      float p1 = exp2f(fmaf(sf[fk][1], C2, -mC));
      float p2 = exp2f(fmaf(sf[fk][2], C2, -mC));
      float p3 = exp2f(fmaf(sf[fk][3], C2, -mC));
      rs += (p0 + p1) + (p2 + p3);
      short4v pk;
      pk[0] = (short)f2bf(p0); pk[1] = (short)f2bf(p1);
      pk[2] = (short)f2bf(p2); pk[3] = (short)f2bf(p3);
      *(short4v*)&Ps[pslot][lr * LDT + fk * 16 + 4 * g] = pk;
    }
    rs += __shfl_xor(rs, 16, 64);
    rs += __shfl_xor(rs, 32, 64);
    l = l * alpha + rs;
#pragma unroll
    for (int kc = 0; kc < 2; ++kc) {
      bf16x8 pf = *(const bf16x8*)&Ps[pslot][lr * LDT + kc * 32 + g * 8];
      __builtin_amdgcn_s_setprio(1);
#pragma unroll
      for (int df = 0; df < 4; ++df) {
        bf16x8 vf = *(const bf16x8*)&Vs[buf][KSW(df * 16 + lr, kc * 4 + g)];
        o[df] = mfma16x16(pf, vf, o[df]);
      }
      __builtin_amdgcn_s_setprio(0);
    }
  };

  const int nt = tB + 1;
  LOADT(0);
  WRITET(0);
  for (int kt = 0; kt < nt; ++kt) {
    const int cur = kt & 1;
    const bool more = (kt + 1 < nt);
    if (more) LOADT(kt + 1);
    __syncthreads();
    if (kt <= tA) COMPUTE(cur, qfA, oA, mA, lA, w, kt == tA);
    COMPUTE(cur, qfB, oB, mB, lB, 4 + w, kt == tB);
    if (more) WRITET(cur ^ 1);
  }

  float iA[4], iB[4];
#pragma unroll
  for (int r = 0; r < 4; ++r) {
    iA[r] = __builtin_amdgcn_rcpf(__shfl(lA, 4 * g + r, 64));
    iB[r] = __builtin_amdgcn_rcpf(__shfl(lB, 4 * g + r, 64));
  }
#pragma unroll
  for (int df = 0; df < 4; ++df)
#pragma unroll
    for (int r = 0; r < 4; ++r) {
      const int d = df * 16 + lr;
      const int qa = tA * 64 + w * 16 + g * 4 + r;
      const int qb2 = tB * 64 + w * 16 + g * 4 + r;
      Ao[((size_t)bh * S_LEN + qa) * DKH + d] = f2bf(oA[df][r] * iA[r]);
      Ao[((size_t)bh * S_LEN + qb2) * DKH + d] = f2bf(oB[df][r] * iB[r]);
    }
}

extern "C" void kernel_launch(void* const* d_in, const int* in_sizes, int n_in,
                              void* d_out, int out_size, void* d_ws, size_t ws_size,
                              hipStream_t stream)
{
  (void)in_sizes; (void)n_in; (void)out_size;
  const float* q  = (const float*)d_in[0];
  const float* k  = (const float*)d_in[1];
  const float* v  = (const float*)d_in[2];
  const float* Wq = (const float*)d_in[4];
  const float* bq = (const float*)d_in[5];
  const float* Wk = (const float*)d_in[6];
  const float* bk = (const float*)d_in[7];
  const float* Wv = (const float*)d_in[8];
  const float* bv = (const float*)d_in[9];
  const float* Wo = (const float*)d_in[10];
  const float* bo = (const float*)d_in[11];

  char* ws = (char*)d_ws;
  const size_t MB = 1024 * 1024;

  if (ws_size >= 56 * MB) {
    u16* Wqb = (u16*)(ws);               // 2 MB each
    u16* Wkb = (u16*)(ws + 2 * MB);
    u16* Wvb = (u16*)(ws + 4 * MB);
    u16* Wob = (u16*)(ws + 6 * MB);
    u16* qb  = (u16*)(ws + 8 * MB);      // 8 MB each (bf16 activations)
    u16* kb  = (u16*)(ws + 16 * MB);
    u16* vb  = (u16*)(ws + 24 * MB);
    u16* Qh  = (u16*)(ws + 32 * MB);
    u16* Kh  = (u16*)(ws + 40 * MB);
    u16* Vt  = (u16*)(ws + 48 * MB);
    u16* Ao  = qb;                       // qb dead after proj -> alias

    conv_bf16<<<dim3(2048, 7), 256, 0, stream>>>(Wq, Wk, Wv, Wo, q, k, v,
                                                 Wqb, Wkb, Wvb, Wob, qb, kb, vb);
    proj_gemm_bf16<<<dim3(8, 32, 3), 256, 0, stream>>>(qb, kb, vb, Wqb, Wkb, Wvb,
                                                       bq, bk, bv, Qh, Kh, Vt);
    attn_fwd<<<dim3(16, 2 * NHEAD), 256, 0, stream>>>(Qh, Kh, Vt, Ao);
    out_gemm<<<dim3(8, 32), 256, 0, stream>>>(Ao, Wob, bo, (float*)d_out);
  } else {
    // R8 fallback (40 MB scratch)
    u16* Wqb = (u16*)(ws);
    u16* Wkb = (u16*)(ws + 2 * MB);
    u16* Wvb = (u16*)(ws + 4 * MB);
    u16* Wob = (u16*)(ws + 6 * MB);
    u16* Qh  = (u16*)(ws + 8 * MB);
    u16* Kh  = (u16*)(ws + 16 * MB);
    u16* Vt  = (u16*)(ws + 24 * MB);
    u16* Ao  = (u16*)(ws + 32 * MB);

    conv_w<<<dim3(512, 4), 256, 0, stream>>>(Wq, Wk, Wv, Wo, Wqb, Wkb, Wvb, Wob);
    proj_gemm_f32<<<dim3(8, 32, 3), 256, 0, stream>>>(q, k, v, Wqb, Wkb, Wvb,
                                                      bq, bk, bv, Qh, Kh, Vt);
    attn_fwd<<<dim3(16, 2 * NHEAD), 256, 0, stream>>>(Qh, Kh, Vt, Ao);
    out_gemm<<<dim3(8, 32), 256, 0, stream>>>(Ao, Wob, bo, (float*)d_out);
  }
}

// Round 15
// 123.256 us; speedup vs baseline: 1.2103x; 1.0072x over previous
//
#include <hip/hip_runtime.h>

// MHA forward: B=2, S=2048, D=1024, H=16, DK=64. fp32 in/out, bf16 MFMA compute.
// R15 = R14 resubmit (container infra failure, no signal).
// R14 = R13 minus s_setprio (unbundling; m190 prior says setprio hurts
// lockstep low-occupancy kernels). Keeps:
//  - K/V LDS XOR swizzle at stride 64 (conflicts 5.95M -> 1.62M, verified R13)
//  - exp2f/fmaf softmax
// GEMMs unchanged from R10.

#define S_LEN 2048
#define NHEAD 16
#define DMODEL 1024
#define DKH 64
#define LDT 88   // Ps row stride (bf16)

typedef unsigned short u16;
typedef __attribute__((ext_vector_type(4))) short short4v;
typedef __attribute__((ext_vector_type(8))) short short8;
typedef __attribute__((ext_vector_type(8))) __bf16 bf16x8;
typedef __attribute__((ext_vector_type(4))) float f32x4;

__device__ inline u16 f2bf(float f) {
  return __builtin_bit_cast(u16, (__bf16)f);   // v_cvt RNE
}

__device__ inline f32x4 mfma16x16(bf16x8 a, bf16x8 b, f32x4 c) {
  return __builtin_amdgcn_mfma_f32_16x16x32_bf16(a, b, c, 0, 0, 0);
}

__device__ inline short8 pack8(float4 a, float4 b) {
  short8 r;
  r[0] = (short)f2bf(a.x); r[1] = (short)f2bf(a.y);
  r[2] = (short)f2bf(a.z); r[3] = (short)f2bf(a.w);
  r[4] = (short)f2bf(b.x); r[5] = (short)f2bf(b.y);
  r[6] = (short)f2bf(b.z); r[7] = (short)f2bf(b.w);
  return r;
}

typedef const __attribute__((address_space(1))) unsigned GU32;
typedef __attribute__((address_space(3))) unsigned LU32;
__device__ inline void gl2lds16(const void* g, void* l) {
  __builtin_amdgcn_global_load_lds((GU32*)g, (LU32*)l, 16, 0, 0);
}

// swizzled elem-offset into a [rows][64] bf16 tile; col8 = 16B-slot index 0..7
#define SWZ(row, col8) (((row) * 8 + ((col8) ^ ((row) & 7))) * 8)

// ---------- f32 -> bf16 conversion: 4 weights (1M) + q,k,v (4M each) ----------
__global__ __launch_bounds__(256)
void conv_bf16(const float* __restrict__ w0, const float* __restrict__ w1,
               const float* __restrict__ w2, const float* __restrict__ w3,
               const float* __restrict__ aq, const float* __restrict__ ak,
               const float* __restrict__ av,
               u16* __restrict__ o0, u16* __restrict__ o1,
               u16* __restrict__ o2, u16* __restrict__ o3,
               u16* __restrict__ oq, u16* __restrict__ ok, u16* __restrict__ ov)
{
  const int y = blockIdx.y;
  const float* s; u16* d; int n;
  switch (y) {
    case 0: s = w0; d = o0; n = 1 << 20; break;
    case 1: s = w1; d = o1; n = 1 << 20; break;
    case 2: s = w2; d = o2; n = 1 << 20; break;
    case 3: s = w3; d = o3; n = 1 << 20; break;
    case 4: s = aq; d = oq; n = 1 << 22; break;
    case 5: s = ak; d = ok; n = 1 << 22; break;
    default: s = av; d = ov; n = 1 << 22; break;
  }
  const int i = (blockIdx.x * 256 + threadIdx.x) * 8;
  if (i >= n) return;
  float4 a = *(const float4*)&s[i];
  float4 b = *(const float4*)&s[i + 4];
  *(short8*)&d[i] = pack8(a, b);
}

// ---------- weight-only conversion (fallback tier) ----------
__global__ __launch_bounds__(256)
void conv_w(const float* __restrict__ w0, const float* __restrict__ w1,
            const float* __restrict__ w2, const float* __restrict__ w3,
            u16* __restrict__ o0, u16* __restrict__ o1,
            u16* __restrict__ o2, u16* __restrict__ o3)
{
  const int z = blockIdx.y;
  const float* s = z == 0 ? w0 : z == 1 ? w1 : z == 2 ? w2 : w3;
  u16* d = z == 0 ? o0 : z == 1 ? o1 : z == 2 ? o2 : o3;
  const int i = (blockIdx.x * 256 + threadIdx.x) * 8;
  float4 a = *(const float4*)&s[i];
  float4 b = *(const float4*)&s[i + 4];
  *(short8*)&d[i] = pack8(a, b);
}

// ---------- batched projection GEMMs, all-bf16, dbuf gl_lds ----------
__global__ __launch_bounds__(256)
void proj_gemm_bf16(const u16* __restrict__ Aqb, const u16* __restrict__ Akb,
                    const u16* __restrict__ Avb,
                    const u16* __restrict__ Bq, const u16* __restrict__ Bk,
                    const u16* __restrict__ Bv,
                    const float* __restrict__ cq, const float* __restrict__ ck,
                    const float* __restrict__ cv,
                    u16* __restrict__ Oq, u16* __restrict__ Ok, u16* __restrict__ Ov)
{
  __shared__ u16 SM[4 * 8192];               // [A0][A1][B0][B1] = 64 KB

  const int hw = blockIdx.x + (blockIdx.y << 3) + (blockIdx.z << 8);  // 0..767
  const int xcd = hw & 7, sq = hw >> 3;
  const int pan = sq % 12, xb = sq / 12;
  const int p = pan * 8 + xcd;
  const int zz = p >> 5, py = p & 31;

  const u16* Ab = zz == 0 ? Aqb : zz == 1 ? Akb : Avb;
  const u16* Wb = zz == 0 ? Bq : zz == 1 ? Bk : Bv;
  const float* bias = zz == 0 ? cq : zz == 1 ? ck : cv;

  const int t = threadIdx.x;
  const int lane = t & 63;
  const int wv = t >> 6;
  const int wm = wv >> 1, wn = wv & 1;
  const int g = lane >> 4, lr = lane & 15;
  const int bm = py << 7, bn = xb << 7;
  const int K = DMODEL;

  auto STAGE = [&](int buf, int kt) {
    const int k0 = kt << 6;
    u16* Asb = SM + buf * 8192;
    u16* Bsb = SM + 16384 + buf * 8192;
#pragma unroll
    for (int i = 0; i < 4; ++i) {
      int c = t + (i << 8);
      int row = c >> 3, col8 = c & 7;
      int c8s = col8 ^ (row & 7);
      gl2lds16(&Ab[(size_t)(bm + row) * K + k0 + c8s * 8], &Asb[c * 8]);
      gl2lds16(&Wb[(size_t)(bn + row) * K + k0 + c8s * 8], &Bsb[c * 8]);
    }
  };

  f32x4 acc[4][4] = {};
  STAGE(0, 0);
  __syncthreads();
  for (int kt = 0; kt < 16; ++kt) {
    const int cur = kt & 1;
    if (kt + 1 < 16) STAGE(cur ^ 1, kt + 1);   // issue-early; drained by barrier
    u16* Asb = SM + cur * 8192;
    u16* Bsb = SM + 16384 + cur * 8192;
    bf16x8 af[2][4], bf[2][4];
#pragma unroll
    for (int kc = 0; kc < 2; ++kc)
#pragma unroll
      for (int f = 0; f < 4; ++f) {
        af[kc][f] = *(const bf16x8*)&Asb[SWZ(wm * 64 + f * 16 + lr, kc * 4 + g)];
        bf[kc][f] = *(const bf16x8*)&Bsb[SWZ(wn * 64 + f * 16 + lr, kc * 4 + g)];
      }
#pragma unroll
    for (int kc = 0; kc < 2; ++kc)
#pragma unroll
      for (int fm = 0; fm < 4; ++fm)
#pragma unroll
        for (int fn = 0; fn < 4; ++fn)
          acc[fm][fn] = mfma16x16(af[kc][fm], bf[kc][fn], acc[fm][fn]);
    __syncthreads();
  }

  if (zz == 2) {
    u16* TL = SM;
    const int b = bm >> 11, s0 = bm & (S_LEN - 1), h0 = bn >> 6;
#pragma unroll
    for (int hh = 0; hh < 2; ++hh) {
      __syncthreads();
      if (wn == hh) {
#pragma unroll
        for (int fm = 0; fm < 4; ++fm)
#pragma unroll
          for (int fn = 0; fn < 4; ++fn) {
            const int lch = fn * 16 + lr;
            const float bb = bias[bn + hh * 64 + lch];
#pragma unroll
            for (int r = 0; r < 4; ++r)
              TL[lch * 132 + wm * 64 + fm * 16 + g * 4 + r] = f2bf(acc[fm][fn][r] + bb);
          }
      }
      __syncthreads();
#pragma unroll
      for (int i = 0; i < 4; ++i) {
        int c = t + (i << 8);
        int dk = c >> 4, sc = (c & 15) << 3;
        short8 vv = *(const short8*)&TL[dk * 132 + sc];
        *(short8*)&Ov[(((size_t)(b * NHEAD + h0 + hh)) * DKH + dk) * S_LEN + s0 + sc] = vv;
      }
    }
  } else {
    u16* Out = zz == 0 ? Oq : Ok;
#pragma unroll
    for (int fm = 0; fm < 4; ++fm)
#pragma unroll
      for (int fn = 0; fn < 4; ++fn) {
        const int col = bn + wn * 64 + fn * 16 + lr;
        const int h = col >> 6, dk = col & (DKH - 1);
        const float bb = bias[col];
#pragma unroll
        for (int r = 0; r < 4; ++r) {
          const int row = bm + wm * 64 + fm * 16 + g * 4 + r;
          const int b = row >> 11, s = row & (S_LEN - 1);
          Out[(((size_t)(b * NHEAD + h)) * S_LEN + s) * DKH + dk] = f2bf(acc[fm][fn][r] + bb);
        }
      }
  }
}

// ---------- R8 proj (fp32 A reg-staged) — fallback tier ----------
__global__ __launch_bounds__(256)
void proj_gemm_f32(const float* __restrict__ Aq, const float* __restrict__ Akk,
                   const float* __restrict__ Av,
                   const u16* __restrict__ Bq, const u16* __restrict__ Bk,
                   const u16* __restrict__ Bv,
                   const float* __restrict__ cq, const float* __restrict__ ck,
                   const float* __restrict__ cv,
                   u16* __restrict__ Oq, u16* __restrict__ Ok, u16* __restrict__ Ov)
{
  __shared__ u16 SM[3 * 8192];
  u16* As = SM;
  u16* Bs0 = SM + 8192;
  u16* Bs1 = SM + 16384;

  const int hw = blockIdx.x + (blockIdx.y << 3) + (blockIdx.z << 8);
  const int xcd = hw & 7, sq = hw >> 3;
  const int pan = sq % 12, xb = sq / 12;
  const int p = pan * 8 + xcd;
  const int zz = p >> 5, py = p & 31;

  const float* Af = zz == 0 ? Aq : zz == 1 ? Akk : Av;
  const u16* Wb = zz == 0 ? Bq : zz == 1 ? Bk : Bv;
  const float* bias = zz == 0 ? cq : zz == 1 ? ck : cv;

  const int t = threadIdx.x;
  const int lane = t & 63;
  const int wv = t >> 6;
  const int wm = wv >> 1, wn = wv & 1;
  const int g = lane >> 4, lr = lane & 15;
  const int bm = py << 7, bn = xb << 7;
  const int K = DMODEL;

  float4 ax[4], ay[4];
  auto ALOAD = [&](int kt) {
    const int k0 = kt << 6;
#pragma unroll
    for (int i = 0; i < 4; ++i) {
      int c = t + (i << 8);
      int row = c >> 3, col8 = c & 7;
      const float* src = &Af[(size_t)(bm + row) * K + k0 + col8 * 8];
      ax[i] = *(const float4*)src;
      ay[i] = *(const float4*)(src + 4);
    }
  };
  auto AWRITE = [&]() {
#pragma unroll
    for (int i = 0; i < 4; ++i) {
      int c = t + (i << 8);
      int row = c >> 3, col8 = c & 7;
      *(short8*)&As[SWZ(row, col8)] = pack8(ax[i], ay[i]);
    }
  };
  auto BSTAGE = [&](u16* buf, int kt) {
    const int k0 = kt << 6;
#pragma unroll
    for (int i = 0; i < 4; ++i) {
      int c = t + (i << 8);
      int row = c >> 3, col8 = c & 7;
      int c8s = col8 ^ (row & 7);
      gl2lds16(&Wb[(size_t)(bn + row) * K + k0 + c8s * 8], &buf[c * 8]);
    }
  };

  f32x4 acc[4][4] = {};
  ALOAD(0);
  BSTAGE(Bs0, 0);
  AWRITE();
  __syncthreads();
  for (int kt = 0; kt < 16; ++kt) {
    u16* Bcur = (kt & 1) ? Bs1 : Bs0;
    u16* Bnxt = (kt & 1) ? Bs0 : Bs1;
    const bool more = (kt + 1 < 16);
    if (more) { ALOAD(kt + 1); BSTAGE(Bnxt, kt + 1); }
    bf16x8 af[2][4], bf[2][4];
#pragma unroll
    for (int kc = 0; kc < 2; ++kc)
#pragma unroll
      for (int f = 0; f < 4; ++f) {
        af[kc][f] = *(const bf16x8*)&As[SWZ(wm * 64 + f * 16 + lr, kc * 4 + g)];
        bf[kc][f] = *(const bf16x8*)&Bcur[SWZ(wn * 64 + f * 16 + lr, kc * 4 + g)];
      }
#pragma unroll
    for (int kc = 0; kc < 2; ++kc)
#pragma unroll
      for (int fm = 0; fm < 4; ++fm)
#pragma unroll
        for (int fn = 0; fn < 4; ++fn)
          acc[fm][fn] = mfma16x16(af[kc][fm], bf[kc][fn], acc[fm][fn]);
    __syncthreads();
    if (more) {
      AWRITE();
      __syncthreads();
    }
  }

  if (zz == 2) {
    u16* TL = SM;
    const int b = bm >> 11, s0 = bm & (S_LEN - 1), h0 = bn >> 6;
#pragma unroll
    for (int hh = 0; hh < 2; ++hh) {
      __syncthreads();
      if (wn == hh) {
#pragma unroll
        for (int fm = 0; fm < 4; ++fm)
#pragma unroll
          for (int fn = 0; fn < 4; ++fn) {
            const int lch = fn * 16 + lr;
            const float bb = bias[bn + hh * 64 + lch];
#pragma unroll
            for (int r = 0; r < 4; ++r)
              TL[lch * 132 + wm * 64 + fm * 16 + g * 4 + r] = f2bf(acc[fm][fn][r] + bb);
          }
      }
      __syncthreads();
#pragma unroll
      for (int i = 0; i < 4; ++i) {
        int c = t + (i << 8);
        int dk = c >> 4, sc = (c & 15) << 3;
        short8 vv = *(const short8*)&TL[dk * 132 + sc];
        *(short8*)&Ov[(((size_t)(b * NHEAD + h0 + hh)) * DKH + dk) * S_LEN + s0 + sc] = vv;
      }
    }
  } else {
    u16* Out = zz == 0 ? Oq : Ok;
#pragma unroll
    for (int fm = 0; fm < 4; ++fm)
#pragma unroll
      for (int fn = 0; fn < 4; ++fn) {
        const int col = bn + wn * 64 + fn * 16 + lr;
        const int h = col >> 6, dk = col & (DKH - 1);
        const float bb = bias[col];
#pragma unroll
        for (int r = 0; r < 4; ++r) {
          const int row = bm + wm * 64 + fm * 16 + g * 4 + r;
          const int b = row >> 11, s = row & (S_LEN - 1);
          Out[(((size_t)(b * NHEAD + h)) * S_LEN + s) * DKH + dk] = f2bf(acc[fm][fn][r] + bb);
        }
      }
  }
}

// ---------- O-projection: Ao(head-split bf16) @ Wo^T + bo -> f32 out ----------
__global__ __launch_bounds__(256)
void out_gemm(const u16* __restrict__ Ao, const u16* __restrict__ Wb,
              const float* __restrict__ bias, float* __restrict__ Out)
{
  __shared__ u16 SM[4 * 8192];
  const int hw = blockIdx.x + (blockIdx.y << 3);
  const int xcd = hw & 7, sq = hw >> 3;
  const int pan = sq & 3, xb = sq >> 2;
  const int prow = pan * 8 + xcd;

  const int t = threadIdx.x;
  const int lane = t & 63;
  const int wv = t >> 6;
  const int wm = wv >> 1, wn = wv & 1;
  const int g = lane >> 4, lr = lane & 15;
  const int bm = prow << 7, bn = xb << 7;
  const int K = DMODEL;

  auto STAGE = [&](int buf, int kt) {
    const int k0 = kt << 6;
    u16* Asb = SM + buf * 8192;
    u16* Bsb = SM + 16384 + buf * 8192;
#pragma unroll
    for (int i = 0; i < 4; ++i) {
      int c = t + (i << 8);
      int row = c >> 3, col8 = c & 7;
      int c8s = col8 ^ (row & 7);
      int grow = bm + row;
      int b = grow >> 11, s = grow & (S_LEN - 1);
      int k = k0 + c8s * 8;
      int h = k >> 6, dk = k & (DKH - 1);
      gl2lds16(&Ao[(((size_t)(b * NHEAD + h)) * S_LEN + s) * DKH + dk], &Asb[c * 8]);
      gl2lds16(&Wb[(size_t)(bn + row) * K + k0 + c8s * 8], &Bsb[c * 8]);
    }
  };

  f32x4 acc[4][4] = {};
  STAGE(0, 0);
  __syncthreads();
  for (int kt = 0; kt < 16; ++kt) {
    const int cur = kt & 1;
    if (kt + 1 < 16) STAGE(cur ^ 1, kt + 1);
    u16* Asb = SM + cur * 8192;
    u16* Bsb = SM + 16384 + cur * 8192;
    bf16x8 af[2][4], bf[2][4];
#pragma unroll
    for (int kc = 0; kc < 2; ++kc)
#pragma unroll
      for (int f = 0; f < 4; ++f) {
        af[kc][f] = *(const bf16x8*)&Asb[SWZ(wm * 64 + f * 16 + lr, kc * 4 + g)];
        bf[kc][f] = *(const bf16x8*)&Bsb[SWZ(wn * 64 + f * 16 + lr, kc * 4 + g)];
      }
#pragma unroll
    for (int kc = 0; kc < 2; ++kc)
#pragma unroll
      for (int fm = 0; fm < 4; ++fm)
#pragma unroll
        for (int fn = 0; fn < 4; ++fn)
          acc[fm][fn] = mfma16x16(af[kc][fm], bf[kc][fn], acc[fm][fn]);
    __syncthreads();
  }
#pragma unroll
  for (int fm = 0; fm < 4; ++fm)
#pragma unroll
    for (int fn = 0; fn < 4; ++fn) {
      const int col = bn + wn * 64 + fn * 16 + lr;
      const float bb = bias[col];
#pragma unroll
      for (int r = 0; r < 4; ++r) {
        const int row = bm + wm * 64 + fm * 16 + g * 4 + r;
        Out[(size_t)row * DMODEL + col] = acc[fm][fn][r] + bb;
      }
    }
}

// ---------- Flash attention, causal, paired {p,31-p}, head-split Ao ----------
// R10 structure; K/V at stride 64 + XOR swizzle; exp2 softmax; NO setprio.
// KSW: elem offset of 16B slot `slot` in swizzled row `row` of a [64][64] tile.
#define KSW(row, slot) (((row) << 6) + ((((slot) ^ ((row) & 7))) << 3))
__global__ __launch_bounds__(256)
void attn_fwd(const u16* __restrict__ Qh, const u16* __restrict__ Kh,
              const u16* __restrict__ Vtg, u16* __restrict__ Ao)
{
  __shared__ u16 Ks[2][64 * 64];
  __shared__ u16 Vs[2][64 * 64];
  __shared__ u16 Ps[8][16 * LDT];
  const int t = threadIdx.x, lane = t & 63, w = t >> 6;
  const int g = lane >> 4, lr = lane & 15;
  const int bh = blockIdx.y;
  const int pA = blockIdx.x;
  const int tA = pA, tB = 31 - pA;
  const u16* Qb = Qh + (size_t)bh * S_LEN * DKH;
  const u16* Kb = Kh + (size_t)bh * S_LEN * DKH;
  const u16* Vb = Vtg + (size_t)bh * DKH * S_LEN;

  bf16x8 qfA[2], qfB[2];
#pragma unroll
  for (int kc = 0; kc < 2; ++kc) {
    qfA[kc] = *(const bf16x8*)&Qb[(size_t)(tA * 64 + w * 16 + lr) * DKH + kc * 32 + g * 8];
    qfB[kc] = *(const bf16x8*)&Qb[(size_t)(tB * 64 + w * 16 + lr) * DKH + kc * 32 + g * 8];
  }

  f32x4 oA[4] = {}, oB[4] = {};
  float mA = -1e30f, lA = 0.f, mB = -1e30f, lB = 0.f;

  const int r0 = t >> 3;            // 0..31
  const int sl0 = t & 7;            // 16B slot 0..7
  short8 kr0, kr1, vr0, vr1;

  auto LOADT = [&](int kt) {
    const int kv0 = kt << 6;
    const int c0 = sl0 << 3;
    kr0 = *(const short8*)&Kb[(size_t)(kv0 + r0) * DKH + c0];
    kr1 = *(const short8*)&Kb[(size_t)(kv0 + r0 + 32) * DKH + c0];
    vr0 = *(const short8*)&Vb[(size_t)r0 * S_LEN + kv0 + c0];
    vr1 = *(const short8*)&Vb[(size_t)(r0 + 32) * S_LEN + kv0 + c0];
  };
  auto WRITET = [&](int b) {
    *(short8*)&Ks[b][KSW(r0, sl0)] = kr0;
    *(short8*)&Ks[b][KSW(r0 + 32, sl0)] = kr1;
    *(short8*)&Vs[b][KSW(r0, sl0)] = vr0;
    *(short8*)&Vs[b][KSW(r0 + 32, sl0)] = vr1;
  };

  const float C2 = 0.18033688011f;  // 0.125 * log2(e)

  auto COMPUTE = [&](int buf, const bf16x8* qf, f32x4* o, float& m, float& l,
                     int pslot, bool diag) {
    // S^T tile: S[kv][q] = mfma(K, Q). lane: kv = fk*16 + 4g + r, q = lr.
    f32x4 sf[4];
#pragma unroll
    for (int fk = 0; fk < 4; ++fk) {
      f32x4 a = {};
#pragma unroll
      for (int kc = 0; kc < 2; ++kc) {
        bf16x8 kf = *(const bf16x8*)&Ks[buf][KSW(fk * 16 + lr, kc * 4 + g)];
        a = mfma16x16(kf, qf[kc], a);
      }
      sf[fk] = a;
    }
    if (diag) {
#pragma unroll
      for (int fk = 0; fk < 4; ++fk)
#pragma unroll
        for (int r = 0; r < 4; ++r)
          if (fk * 16 + 4 * g + r > w * 16 + lr) sf[fk][r] = -1e30f;
    }
    float pm = fmaxf(fmaxf(sf[0][0], sf[0][1]), fmaxf(sf[0][2], sf[0][3]));
#pragma unroll
    for (int fk = 1; fk < 4; ++fk)
      pm = fmaxf(pm, fmaxf(fmaxf(sf[fk][0], sf[fk][1]), fmaxf(sf[fk][2], sf[fk][3])));
    pm = fmaxf(pm, __shfl_xor(pm, 16, 64));
    pm = fmaxf(pm, __shfl_xor(pm, 32, 64));
    float alpha = 1.0f;
    if (!__all(pm - m <= 64.0f)) {            // defer-rescale (raw thr 64 = 8/8)
      float mn = fmaxf(m, pm);
      alpha = exp2f((m - mn) * C2);
      m = mn;
#pragma unroll
      for (int r = 0; r < 4; ++r) {
        float ar = __shfl(alpha, 4 * g + r, 64);
#pragma unroll
        for (int d = 0; d < 4; ++d) o[d][r] *= ar;
      }
    }
    const float mC = m * C2;
    float rs = 0.f;
#pragma unroll
    for (int fk = 0; fk < 4; ++fk) {
      float p0 = exp2f(fmaf(sf[fk][0], C2, -mC));
      float p1 = exp2f(fmaf(sf[fk][1], C2, -mC));
      float p2 = exp2f(fmaf(sf[fk][2], C2, -mC));
      float p3 = exp2f(fmaf(sf[fk][3], C2, -mC));
      rs += (p0 + p1) + (p2 + p3);
      short4v pk;
      pk[0] = (short)f2bf(p0); pk[1] = (short)f2bf(p1);
      pk[2] = (short)f2bf(p2); pk[3] = (short)f2bf(p3);
      *(short4v*)&Ps[pslot][lr * LDT + fk * 16 + 4 * g] = pk;
    }
    rs += __shfl_xor(rs, 16, 64);
    rs += __shfl_xor(rs, 32, 64);
    l = l * alpha + rs;
#pragma unroll
    for (int kc = 0; kc < 2; ++kc) {
      bf16x8 pf = *(const bf16x8*)&Ps[pslot][lr * LDT + kc * 32 + g * 8];
#pragma unroll
      for (int df = 0; df < 4; ++df) {
        bf16x8 vf = *(const bf16x8*)&Vs[buf][KSW(df * 16 + lr, kc * 4 + g)];
        o[df] = mfma16x16(pf, vf, o[df]);
      }
    }
  };

  const int nt = tB + 1;
  LOADT(0);
  WRITET(0);
  for (int kt = 0; kt < nt; ++kt) {
    const int cur = kt & 1;
    const bool more = (kt + 1 < nt);
    if (more) LOADT(kt + 1);
    __syncthreads();
    if (kt <= tA) COMPUTE(cur, qfA, oA, mA, lA, w, kt == tA);
    COMPUTE(cur, qfB, oB, mB, lB, 4 + w, kt == tB);
    if (more) WRITET(cur ^ 1);
  }

  float iA[4], iB[4];
#pragma unroll
  for (int r = 0; r < 4; ++r) {
    iA[r] = __builtin_amdgcn_rcpf(__shfl(lA, 4 * g + r, 64));
    iB[r] = __builtin_amdgcn_rcpf(__shfl(lB, 4 * g + r, 64));
  }
#pragma unroll
  for (int df = 0; df < 4; ++df)
#pragma unroll
    for (int r = 0; r < 4; ++r) {
      const int d = df * 16 + lr;
      const int qa = tA * 64 + w * 16 + g * 4 + r;
      const int qb2 = tB * 64 + w * 16 + g * 4 + r;
      Ao[((size_t)bh * S_LEN + qa) * DKH + d] = f2bf(oA[df][r] * iA[r]);
      Ao[((size_t)bh * S_LEN + qb2) * DKH + d] = f2bf(oB[df][r] * iB[r]);
    }
}

extern "C" void kernel_launch(void* const* d_in, const int* in_sizes, int n_in,
                              void* d_out, int out_size, void* d_ws, size_t ws_size,
                              hipStream_t stream)
{
  (void)in_sizes; (void)n_in; (void)out_size;
  const float* q  = (const float*)d_in[0];
  const float* k  = (const float*)d_in[1];
  const float* v  = (const float*)d_in[2];
  const float* Wq = (const float*)d_in[4];
  const float* bq = (const float*)d_in[5];
  const float* Wk = (const float*)d_in[6];
  const float* bk = (const float*)d_in[7];
  const float* Wv = (const float*)d_in[8];
  const float* bv = (const float*)d_in[9];
  const float* Wo = (const float*)d_in[10];
  const float* bo = (const float*)d_in[11];

  char* ws = (char*)d_ws;
  const size_t MB = 1024 * 1024;

  if (ws_size >= 56 * MB) {
    u16* Wqb = (u16*)(ws);               // 2 MB each
    u16* Wkb = (u16*)(ws + 2 * MB);
    u16* Wvb = (u16*)(ws + 4 * MB);
    u16* Wob = (u16*)(ws + 6 * MB);
    u16* qb  = (u16*)(ws + 8 * MB);      // 8 MB each (bf16 activations)
    u16* kb  = (u16*)(ws + 16 * MB);
    u16* vb  = (u16*)(ws + 24 * MB);
    u16* Qh  = (u16*)(ws + 32 * MB);
    u16* Kh  = (u16*)(ws + 40 * MB);
    u16* Vt  = (u16*)(ws + 48 * MB);
    u16* Ao  = qb;                       // qb dead after proj -> alias

    conv_bf16<<<dim3(2048, 7), 256, 0, stream>>>(Wq, Wk, Wv, Wo, q, k, v,
                                                 Wqb, Wkb, Wvb, Wob, qb, kb, vb);
    proj_gemm_bf16<<<dim3(8, 32, 3), 256, 0, stream>>>(qb, kb, vb, Wqb, Wkb, Wvb,
                                                       bq, bk, bv, Qh, Kh, Vt);
    attn_fwd<<<dim3(16, 2 * NHEAD), 256, 0, stream>>>(Qh, Kh, Vt, Ao);
    out_gemm<<<dim3(8, 32), 256, 0, stream>>>(Ao, Wob, bo, (float*)d_out);
  } else {
    // R8 fallback (40 MB scratch)
    u16* Wqb = (u16*)(ws);
    u16* Wkb = (u16*)(ws + 2 * MB);
    u16* Wvb = (u16*)(ws + 4 * MB);
    u16* Wob = (u16*)(ws + 6 * MB);
    u16* Qh  = (u16*)(ws + 8 * MB);
    u16* Kh  = (u16*)(ws + 16 * MB);
    u16* Vt  = (u16*)(ws + 24 * MB);
    u16* Ao  = (u16*)(ws + 32 * MB);

    conv_w<<<dim3(512, 4), 256, 0, stream>>>(Wq, Wk, Wv, Wo, Wqb, Wkb, Wvb, Wob);
    proj_gemm_f32<<<dim3(8, 32, 3), 256, 0, stream>>>(q, k, v, Wqb, Wkb, Wvb,
                                                      bq, bk, bv, Qh, Kh, Vt);
    attn_fwd<<<dim3(16, 2 * NHEAD), 256, 0, stream>>>(Qh, Kh, Vt, Ao);
    out_gemm<<<dim3(8, 32), 256, 0, stream>>>(Ao, Wob, bo, (float*)d_out);
  }
}

// Round 18
// 120.433 us; speedup vs baseline: 1.2387x; 1.0234x over previous
//
#include <hip/hip_runtime.h>

// MHA forward: B=2, S=2048, D=1024, H=16, DK=64. fp32 in/out, bf16 MFMA compute.
// R18 = exact R10 restore, 3rd submit (container infra failures on R16/R17).
// Ledger: attn KSW-swizzle+exp2 = net -3us (R13/R15); setprio neutral (R15);
// 32x32 ports regress (R11 imbalance, R12 occupancy). R10 = measured best.

#define S_LEN 2048
#define NHEAD 16
#define DMODEL 1024
#define DKH 64
#define LDT 88   // padded LDS row stride for attn tiles

typedef unsigned short u16;
typedef __attribute__((ext_vector_type(4))) short short4v;
typedef __attribute__((ext_vector_type(8))) short short8;
typedef __attribute__((ext_vector_type(8))) __bf16 bf16x8;
typedef __attribute__((ext_vector_type(4))) float f32x4;

__device__ inline u16 f2bf(float f) {
  return __builtin_bit_cast(u16, (__bf16)f);   // v_cvt RNE
}

__device__ inline f32x4 mfma16x16(bf16x8 a, bf16x8 b, f32x4 c) {
  return __builtin_amdgcn_mfma_f32_16x16x32_bf16(a, b, c, 0, 0, 0);
}

__device__ inline short8 pack8(float4 a, float4 b) {
  short8 r;
  r[0] = (short)f2bf(a.x); r[1] = (short)f2bf(a.y);
  r[2] = (short)f2bf(a.z); r[3] = (short)f2bf(a.w);
  r[4] = (short)f2bf(b.x); r[5] = (short)f2bf(b.y);
  r[6] = (short)f2bf(b.z); r[7] = (short)f2bf(b.w);
  return r;
}

typedef const __attribute__((address_space(1))) unsigned GU32;
typedef __attribute__((address_space(3))) unsigned LU32;
__device__ inline void gl2lds16(const void* g, void* l) {
  __builtin_amdgcn_global_load_lds((GU32*)g, (LU32*)l, 16, 0, 0);
}

// swizzled elem-offset into a [rows][64] bf16 tile; col8 = 16B-slot index 0..7
#define SWZ(row, col8) (((row) * 8 + ((col8) ^ ((row) & 7))) * 8)

// ---------- f32 -> bf16 conversion: 4 weights (1M) + q,k,v (4M each) ----------
__global__ __launch_bounds__(256)
void conv_bf16(const float* __restrict__ w0, const float* __restrict__ w1,
               const float* __restrict__ w2, const float* __restrict__ w3,
               const float* __restrict__ aq, const float* __restrict__ ak,
               const float* __restrict__ av,
               u16* __restrict__ o0, u16* __restrict__ o1,
               u16* __restrict__ o2, u16* __restrict__ o3,
               u16* __restrict__ oq, u16* __restrict__ ok, u16* __restrict__ ov)
{
  const int y = blockIdx.y;
  const float* s; u16* d; int n;
  switch (y) {
    case 0: s = w0; d = o0; n = 1 << 20; break;
    case 1: s = w1; d = o1; n = 1 << 20; break;
    case 2: s = w2; d = o2; n = 1 << 20; break;
    case 3: s = w3; d = o3; n = 1 << 20; break;
    case 4: s = aq; d = oq; n = 1 << 22; break;
    case 5: s = ak; d = ok; n = 1 << 22; break;
    default: s = av; d = ov; n = 1 << 22; break;
  }
  const int i = (blockIdx.x * 256 + threadIdx.x) * 8;
  if (i >= n) return;
  float4 a = *(const float4*)&s[i];
  float4 b = *(const float4*)&s[i + 4];
  *(short8*)&d[i] = pack8(a, b);
}

// ---------- weight-only conversion (fallback tier) ----------
__global__ __launch_bounds__(256)
void conv_w(const float* __restrict__ w0, const float* __restrict__ w1,
            const float* __restrict__ w2, const float* __restrict__ w3,
            u16* __restrict__ o0, u16* __restrict__ o1,
            u16* __restrict__ o2, u16* __restrict__ o3)
{
  const int z = blockIdx.y;
  const float* s = z == 0 ? w0 : z == 1 ? w1 : z == 2 ? w2 : w3;
  u16* d = z == 0 ? o0 : z == 1 ? o1 : z == 2 ? o2 : o3;
  const int i = (blockIdx.x * 256 + threadIdx.x) * 8;
  float4 a = *(const float4*)&s[i];
  float4 b = *(const float4*)&s[i + 4];
  *(short8*)&d[i] = pack8(a, b);
}

// ---------- batched projection GEMMs, all-bf16, dbuf gl_lds ----------
__global__ __launch_bounds__(256)
void proj_gemm_bf16(const u16* __restrict__ Aqb, const u16* __restrict__ Akb,
                    const u16* __restrict__ Avb,
                    const u16* __restrict__ Bq, const u16* __restrict__ Bk,
                    const u16* __restrict__ Bv,
                    const float* __restrict__ cq, const float* __restrict__ ck,
                    const float* __restrict__ cv,
                    u16* __restrict__ Oq, u16* __restrict__ Ok, u16* __restrict__ Ov)
{
  __shared__ u16 SM[4 * 8192];               // [A0][A1][B0][B1] = 64 KB

  const int hw = blockIdx.x + (blockIdx.y << 3) + (blockIdx.z << 8);  // 0..767
  const int xcd = hw & 7, sq = hw >> 3;
  const int pan = sq % 12, xb = sq / 12;
  const int p = pan * 8 + xcd;
  const int zz = p >> 5, py = p & 31;

  const u16* Ab = zz == 0 ? Aqb : zz == 1 ? Akb : Avb;
  const u16* Wb = zz == 0 ? Bq : zz == 1 ? Bk : Bv;
  const float* bias = zz == 0 ? cq : zz == 1 ? ck : cv;

  const int t = threadIdx.x;
  const int lane = t & 63;
  const int wv = t >> 6;
  const int wm = wv >> 1, wn = wv & 1;
  const int g = lane >> 4, lr = lane & 15;
  const int bm = py << 7, bn = xb << 7;
  const int K = DMODEL;

  auto STAGE = [&](int buf, int kt) {
    const int k0 = kt << 6;
    u16* Asb = SM + buf * 8192;
    u16* Bsb = SM + 16384 + buf * 8192;
#pragma unroll
    for (int i = 0; i < 4; ++i) {
      int c = t + (i << 8);
      int row = c >> 3, col8 = c & 7;
      int c8s = col8 ^ (row & 7);
      gl2lds16(&Ab[(size_t)(bm + row) * K + k0 + c8s * 8], &Asb[c * 8]);
      gl2lds16(&Wb[(size_t)(bn + row) * K + k0 + c8s * 8], &Bsb[c * 8]);
    }
  };

  f32x4 acc[4][4] = {};
  STAGE(0, 0);
  __syncthreads();
  for (int kt = 0; kt < 16; ++kt) {
    const int cur = kt & 1;
    if (kt + 1 < 16) STAGE(cur ^ 1, kt + 1);   // issue-early; drained by barrier
    u16* Asb = SM + cur * 8192;
    u16* Bsb = SM + 16384 + cur * 8192;
    bf16x8 af[2][4], bf[2][4];
#pragma unroll
    for (int kc = 0; kc < 2; ++kc)
#pragma unroll
      for (int f = 0; f < 4; ++f) {
        af[kc][f] = *(const bf16x8*)&Asb[SWZ(wm * 64 + f * 16 + lr, kc * 4 + g)];
        bf[kc][f] = *(const bf16x8*)&Bsb[SWZ(wn * 64 + f * 16 + lr, kc * 4 + g)];
      }
#pragma unroll
    for (int kc = 0; kc < 2; ++kc)
#pragma unroll
      for (int fm = 0; fm < 4; ++fm)
#pragma unroll
        for (int fn = 0; fn < 4; ++fn)
          acc[fm][fn] = mfma16x16(af[kc][fm], bf[kc][fn], acc[fm][fn]);
    __syncthreads();
  }

  if (zz == 2) {
    u16* TL = SM;
    const int b = bm >> 11, s0 = bm & (S_LEN - 1), h0 = bn >> 6;
#pragma unroll
    for (int hh = 0; hh < 2; ++hh) {
      __syncthreads();
      if (wn == hh) {
#pragma unroll
        for (int fm = 0; fm < 4; ++fm)
#pragma unroll
          for (int fn = 0; fn < 4; ++fn) {
            const int lch = fn * 16 + lr;
            const float bb = bias[bn + hh * 64 + lch];
#pragma unroll
            for (int r = 0; r < 4; ++r)
              TL[lch * 132 + wm * 64 + fm * 16 + g * 4 + r] = f2bf(acc[fm][fn][r] + bb);
          }
      }
      __syncthreads();
#pragma unroll
      for (int i = 0; i < 4; ++i) {
        int c = t + (i << 8);
        int dk = c >> 4, sc = (c & 15) << 3;
        short8 vv = *(const short8*)&TL[dk * 132 + sc];
        *(short8*)&Ov[(((size_t)(b * NHEAD + h0 + hh)) * DKH + dk) * S_LEN + s0 + sc] = vv;
      }
    }
  } else {
    u16* Out = zz == 0 ? Oq : Ok;
#pragma unroll
    for (int fm = 0; fm < 4; ++fm)
#pragma unroll
      for (int fn = 0; fn < 4; ++fn) {
        const int col = bn + wn * 64 + fn * 16 + lr;
        const int h = col >> 6, dk = col & (DKH - 1);
        const float bb = bias[col];
#pragma unroll
        for (int r = 0; r < 4; ++r) {
          const int row = bm + wm * 64 + fm * 16 + g * 4 + r;
          const int b = row >> 11, s = row & (S_LEN - 1);
          Out[(((size_t)(b * NHEAD + h)) * S_LEN + s) * DKH + dk] = f2bf(acc[fm][fn][r] + bb);
        }
      }
  }
}

// ---------- R8 proj (fp32 A reg-staged) — fallback tier ----------
__global__ __launch_bounds__(256)
void proj_gemm_f32(const float* __restrict__ Aq, const float* __restrict__ Akk,
                   const float* __restrict__ Av,
                   const u16* __restrict__ Bq, const u16* __restrict__ Bk,
                   const u16* __restrict__ Bv,
                   const float* __restrict__ cq, const float* __restrict__ ck,
                   const float* __restrict__ cv,
                   u16* __restrict__ Oq, u16* __restrict__ Ok, u16* __restrict__ Ov)
{
  __shared__ u16 SM[3 * 8192];
  u16* As = SM;
  u16* Bs0 = SM + 8192;
  u16* Bs1 = SM + 16384;

  const int hw = blockIdx.x + (blockIdx.y << 3) + (blockIdx.z << 8);
  const int xcd = hw & 7, sq = hw >> 3;
  const int pan = sq % 12, xb = sq / 12;
  const int p = pan * 8 + xcd;
  const int zz = p >> 5, py = p & 31;

  const float* Af = zz == 0 ? Aq : zz == 1 ? Akk : Av;
  const u16* Wb = zz == 0 ? Bq : zz == 1 ? Bk : Bv;
  const float* bias = zz == 0 ? cq : zz == 1 ? ck : cv;

  const int t = threadIdx.x;
  const int lane = t & 63;
  const int wv = t >> 6;
  const int wm = wv >> 1, wn = wv & 1;
  const int g = lane >> 4, lr = lane & 15;
  const int bm = py << 7, bn = xb << 7;
  const int K = DMODEL;

  float4 ax[4], ay[4];
  auto ALOAD = [&](int kt) {
    const int k0 = kt << 6;
#pragma unroll
    for (int i = 0; i < 4; ++i) {
      int c = t + (i << 8);
      int row = c >> 3, col8 = c & 7;
      const float* src = &Af[(size_t)(bm + row) * K + k0 + col8 * 8];
      ax[i] = *(const float4*)src;
      ay[i] = *(const float4*)(src + 4);
    }
  };
  auto AWRITE = [&]() {
#pragma unroll
    for (int i = 0; i < 4; ++i) {
      int c = t + (i << 8);
      int row = c >> 3, col8 = c & 7;
      *(short8*)&As[SWZ(row, col8)] = pack8(ax[i], ay[i]);
    }
  };
  auto BSTAGE = [&](u16* buf, int kt) {
    const int k0 = kt << 6;
#pragma unroll
    for (int i = 0; i < 4; ++i) {
      int c = t + (i << 8);
      int row = c >> 3, col8 = c & 7;
      int c8s = col8 ^ (row & 7);
      gl2lds16(&Wb[(size_t)(bn + row) * K + k0 + c8s * 8], &buf[c * 8]);
    }
  };

  f32x4 acc[4][4] = {};
  ALOAD(0);
  BSTAGE(Bs0, 0);
  AWRITE();
  __syncthreads();
  for (int kt = 0; kt < 16; ++kt) {
    u16* Bcur = (kt & 1) ? Bs1 : Bs0;
    u16* Bnxt = (kt & 1) ? Bs0 : Bs1;
    const bool more = (kt + 1 < 16);
    if (more) { ALOAD(kt + 1); BSTAGE(Bnxt, kt + 1); }
    bf16x8 af[2][4], bf[2][4];
#pragma unroll
    for (int kc = 0; kc < 2; ++kc)
#pragma unroll
      for (int f = 0; f < 4; ++f) {
        af[kc][f] = *(const bf16x8*)&As[SWZ(wm * 64 + f * 16 + lr, kc * 4 + g)];
        bf[kc][f] = *(const bf16x8*)&Bcur[SWZ(wn * 64 + f * 16 + lr, kc * 4 + g)];
      }
#pragma unroll
    for (int kc = 0; kc < 2; ++kc)
#pragma unroll
      for (int fm = 0; fm < 4; ++fm)
#pragma unroll
        for (int fn = 0; fn < 4; ++fn)
          acc[fm][fn] = mfma16x16(af[kc][fm], bf[kc][fn], acc[fm][fn]);
    __syncthreads();
    if (more) {
      AWRITE();
      __syncthreads();
    }
  }

  if (zz == 2) {
    u16* TL = SM;
    const int b = bm >> 11, s0 = bm & (S_LEN - 1), h0 = bn >> 6;
#pragma unroll
    for (int hh = 0; hh < 2; ++hh) {
      __syncthreads();
      if (wn == hh) {
#pragma unroll
        for (int fm = 0; fm < 4; ++fm)
#pragma unroll
          for (int fn = 0; fn < 4; ++fn) {
            const int lch = fn * 16 + lr;
            const float bb = bias[bn + hh * 64 + lch];
#pragma unroll
            for (int r = 0; r < 4; ++r)
              TL[lch * 132 + wm * 64 + fm * 16 + g * 4 + r] = f2bf(acc[fm][fn][r] + bb);
          }
      }
      __syncthreads();
#pragma unroll
      for (int i = 0; i < 4; ++i) {
        int c = t + (i << 8);
        int dk = c >> 4, sc = (c & 15) << 3;
        short8 vv = *(const short8*)&TL[dk * 132 + sc];
        *(short8*)&Ov[(((size_t)(b * NHEAD + h0 + hh)) * DKH + dk) * S_LEN + s0 + sc] = vv;
      }
    }
  } else {
    u16* Out = zz == 0 ? Oq : Ok;
#pragma unroll
    for (int fm = 0; fm < 4; ++fm)
#pragma unroll
      for (int fn = 0; fn < 4; ++fn) {
        const int col = bn + wn * 64 + fn * 16 + lr;
        const int h = col >> 6, dk = col & (DKH - 1);
        const float bb = bias[col];
#pragma unroll
        for (int r = 0; r < 4; ++r) {
          const int row = bm + wm * 64 + fm * 16 + g * 4 + r;
          const int b = row >> 11, s = row & (S_LEN - 1);
          Out[(((size_t)(b * NHEAD + h)) * S_LEN + s) * DKH + dk] = f2bf(acc[fm][fn][r] + bb);
        }
      }
  }
}

// ---------- O-projection: Ao(head-split bf16) @ Wo^T + bo -> f32 out ----------
__global__ __launch_bounds__(256)
void out_gemm(const u16* __restrict__ Ao, const u16* __restrict__ Wb,
              const float* __restrict__ bias, float* __restrict__ Out)
{
  __shared__ u16 SM[4 * 8192];
  const int hw = blockIdx.x + (blockIdx.y << 3);
  const int xcd = hw & 7, sq = hw >> 3;
  const int pan = sq & 3, xb = sq >> 2;
  const int prow = pan * 8 + xcd;

  const int t = threadIdx.x;
  const int lane = t & 63;
  const int wv = t >> 6;
  const int wm = wv >> 1, wn = wv & 1;
  const int g = lane >> 4, lr = lane & 15;
  const int bm = prow << 7, bn = xb << 7;
  const int K = DMODEL;

  auto STAGE = [&](int buf, int kt) {
    const int k0 = kt << 6;
    u16* Asb = SM + buf * 8192;
    u16* Bsb = SM + 16384 + buf * 8192;
#pragma unroll
    for (int i = 0; i < 4; ++i) {
      int c = t + (i << 8);
      int row = c >> 3, col8 = c & 7;
      int c8s = col8 ^ (row & 7);
      int grow = bm + row;
      int b = grow >> 11, s = grow & (S_LEN - 1);
      int k = k0 + c8s * 8;
      int h = k >> 6, dk = k & (DKH - 1);
      gl2lds16(&Ao[(((size_t)(b * NHEAD + h)) * S_LEN + s) * DKH + dk], &Asb[c * 8]);
      gl2lds16(&Wb[(size_t)(bn + row) * K + k0 + c8s * 8], &Bsb[c * 8]);
    }
  };

  f32x4 acc[4][4] = {};
  STAGE(0, 0);
  __syncthreads();
  for (int kt = 0; kt < 16; ++kt) {
    const int cur = kt & 1;
    if (kt + 1 < 16) STAGE(cur ^ 1, kt + 1);
    u16* Asb = SM + cur * 8192;
    u16* Bsb = SM + 16384 + cur * 8192;
    bf16x8 af[2][4], bf[2][4];
#pragma unroll
    for (int kc = 0; kc < 2; ++kc)
#pragma unroll
      for (int f = 0; f < 4; ++f) {
        af[kc][f] = *(const bf16x8*)&Asb[SWZ(wm * 64 + f * 16 + lr, kc * 4 + g)];
        bf[kc][f] = *(const bf16x8*)&Bsb[SWZ(wn * 64 + f * 16 + lr, kc * 4 + g)];
      }
#pragma unroll
    for (int kc = 0; kc < 2; ++kc)
#pragma unroll
      for (int fm = 0; fm < 4; ++fm)
#pragma unroll
        for (int fn = 0; fn < 4; ++fn)
          acc[fm][fn] = mfma16x16(af[kc][fm], bf[kc][fn], acc[fm][fn]);
    __syncthreads();
  }
#pragma unroll
  for (int fm = 0; fm < 4; ++fm)
#pragma unroll
    for (int fn = 0; fn < 4; ++fn) {
      const int col = bn + wn * 64 + fn * 16 + lr;
      const float bb = bias[col];
#pragma unroll
      for (int r = 0; r < 4; ++r) {
        const int row = bm + wm * 64 + fm * 16 + g * 4 + r;
        Out[(size_t)row * DMODEL + col] = acc[fm][fn][r] + bb;
      }
    }
}

// ---------- Flash attention (exact R10), causal, paired {p,31-p} ----------
// Swapped QK^T: S[kv][q]; scalar m,l; defer-rescale; LDT=88 linear K/V.
__global__ __launch_bounds__(256)
void attn_fwd(const u16* __restrict__ Qh, const u16* __restrict__ Kh,
              const u16* __restrict__ Vtg, u16* __restrict__ Ao)
{
  __shared__ u16 Ks[2][64 * LDT];
  __shared__ u16 Vs[2][64 * LDT];
  __shared__ u16 Ps[8][16 * LDT];
  const int t = threadIdx.x, lane = t & 63, w = t >> 6;
  const int g = lane >> 4, lr = lane & 15;
  const int bh = blockIdx.y;
  const int pA = blockIdx.x;
  const int tA = pA, tB = 31 - pA;
  const u16* Qb = Qh + (size_t)bh * S_LEN * DKH;
  const u16* Kb = Kh + (size_t)bh * S_LEN * DKH;
  const u16* Vb = Vtg + (size_t)bh * DKH * S_LEN;

  bf16x8 qfA[2], qfB[2];
#pragma unroll
  for (int kc = 0; kc < 2; ++kc) {
    qfA[kc] = *(const bf16x8*)&Qb[(size_t)(tA * 64 + w * 16 + lr) * DKH + kc * 32 + g * 8];
    qfB[kc] = *(const bf16x8*)&Qb[(size_t)(tB * 64 + w * 16 + lr) * DKH + kc * 32 + g * 8];
  }

  f32x4 oA[4] = {}, oB[4] = {};
  float mA = -1e30f, lA = 0.f, mB = -1e30f, lB = 0.f;

  const int r0 = t >> 3;
  const int c0 = (t & 7) << 3;
  short8 kr0, kr1, vr0, vr1;

  auto LOADT = [&](int kt) {
    const int kv0 = kt << 6;
    kr0 = *(const short8*)&Kb[(size_t)(kv0 + r0) * DKH + c0];
    kr1 = *(const short8*)&Kb[(size_t)(kv0 + r0 + 32) * DKH + c0];
    vr0 = *(const short8*)&Vb[(size_t)r0 * S_LEN + kv0 + c0];
    vr1 = *(const short8*)&Vb[(size_t)(r0 + 32) * S_LEN + kv0 + c0];
  };
  auto WRITET = [&](int b) {
    *(short8*)&Ks[b][r0 * LDT + c0] = kr0;
    *(short8*)&Ks[b][(r0 + 32) * LDT + c0] = kr1;
    *(short8*)&Vs[b][r0 * LDT + c0] = vr0;
    *(short8*)&Vs[b][(r0 + 32) * LDT + c0] = vr1;
  };

  auto COMPUTE = [&](int buf, const bf16x8* qf, f32x4* o, float& m, float& l,
                     int pslot, bool diag) {
    f32x4 sf[4];
#pragma unroll
    for (int fk = 0; fk < 4; ++fk) {
      f32x4 a = {};
#pragma unroll
      for (int kc = 0; kc < 2; ++kc) {
        bf16x8 kf = *(const bf16x8*)&Ks[buf][(fk * 16 + lr) * LDT + kc * 32 + g * 8];
        a = mfma16x16(kf, qf[kc], a);
      }
      sf[fk] = a;
    }
    if (diag) {
#pragma unroll
      for (int fk = 0; fk < 4; ++fk)
#pragma unroll
        for (int r = 0; r < 4; ++r)
          if (fk * 16 + 4 * g + r > w * 16 + lr) sf[fk][r] = -1e30f;
    }
    float pm = fmaxf(fmaxf(sf[0][0], sf[0][1]), fmaxf(sf[0][2], sf[0][3]));
#pragma unroll
    for (int fk = 1; fk < 4; ++fk)
      pm = fmaxf(pm, fmaxf(fmaxf(sf[fk][0], sf[fk][1]), fmaxf(sf[fk][2], sf[fk][3])));
    pm = fmaxf(pm, __shfl_xor(pm, 16, 64));
    pm = fmaxf(pm, __shfl_xor(pm, 32, 64));
    float alpha = 1.0f;
    if (!__all(pm - m <= 64.0f)) {
      float mn = fmaxf(m, pm);
      alpha = __expf((m - mn) * 0.125f);
      m = mn;
#pragma unroll
      for (int r = 0; r < 4; ++r) {
        float ar = __shfl(alpha, 4 * g + r, 64);
#pragma unroll
        for (int d = 0; d < 4; ++d) o[d][r] *= ar;
      }
    }
    float rs = 0.f;
#pragma unroll
    for (int fk = 0; fk < 4; ++fk) {
      float p0 = __expf((sf[fk][0] - m) * 0.125f);
      float p1 = __expf((sf[fk][1] - m) * 0.125f);
      float p2 = __expf((sf[fk][2] - m) * 0.125f);
      float p3 = __expf((sf[fk][3] - m) * 0.125f);
      rs += (p0 + p1) + (p2 + p3);
      short4v pk;
      pk[0] = (short)f2bf(p0); pk[1] = (short)f2bf(p1);
      pk[2] = (short)f2bf(p2); pk[3] = (short)f2bf(p3);
      *(short4v*)&Ps[pslot][lr * LDT + fk * 16 + 4 * g] = pk;
    }
    rs += __shfl_xor(rs, 16, 64);
    rs += __shfl_xor(rs, 32, 64);
    l = l * alpha + rs;
#pragma unroll
    for (int kc = 0; kc < 2; ++kc) {
      bf16x8 pf = *(const bf16x8*)&Ps[pslot][lr * LDT + kc * 32 + g * 8];
#pragma unroll
      for (int df = 0; df < 4; ++df) {
        bf16x8 vf = *(const bf16x8*)&Vs[buf][(df * 16 + lr) * LDT + kc * 32 + g * 8];
        o[df] = mfma16x16(pf, vf, o[df]);
      }
    }
  };

  const int nt = tB + 1;
  LOADT(0);
  WRITET(0);
  for (int kt = 0; kt < nt; ++kt) {
    const int cur = kt & 1;
    const bool more = (kt + 1 < nt);
    if (more) LOADT(kt + 1);
    __syncthreads();
    if (kt <= tA) COMPUTE(cur, qfA, oA, mA, lA, w, kt == tA);
    COMPUTE(cur, qfB, oB, mB, lB, 4 + w, kt == tB);
    if (more) WRITET(cur ^ 1);
  }

  float iA[4], iB[4];
#pragma unroll
  for (int r = 0; r < 4; ++r) {
    iA[r] = __builtin_amdgcn_rcpf(__shfl(lA, 4 * g + r, 64));
    iB[r] = __builtin_amdgcn_rcpf(__shfl(lB, 4 * g + r, 64));
  }
#pragma unroll
  for (int df = 0; df < 4; ++df)
#pragma unroll
    for (int r = 0; r < 4; ++r) {
      const int d = df * 16 + lr;
      const int qa = tA * 64 + w * 16 + g * 4 + r;
      const int qb2 = tB * 64 + w * 16 + g * 4 + r;
      Ao[((size_t)bh * S_LEN + qa) * DKH + d] = f2bf(oA[df][r] * iA[r]);
      Ao[((size_t)bh * S_LEN + qb2) * DKH + d] = f2bf(oB[df][r] * iB[r]);
    }
}

extern "C" void kernel_launch(void* const* d_in, const int* in_sizes, int n_in,
                              void* d_out, int out_size, void* d_ws, size_t ws_size,
                              hipStream_t stream)
{
  (void)in_sizes; (void)n_in; (void)out_size;
  const float* q  = (const float*)d_in[0];
  const float* k  = (const float*)d_in[1];
  const float* v  = (const float*)d_in[2];
  const float* Wq = (const float*)d_in[4];
  const float* bq = (const float*)d_in[5];
  const float* Wk = (const float*)d_in[6];
  const float* bk = (const float*)d_in[7];
  const float* Wv = (const float*)d_in[8];
  const float* bv = (const float*)d_in[9];
  const float* Wo = (const float*)d_in[10];
  const float* bo = (const float*)d_in[11];

  char* ws = (char*)d_ws;
  const size_t MB = 1024 * 1024;

  if (ws_size >= 56 * MB) {
    u16* Wqb = (u16*)(ws);               // 2 MB each
    u16* Wkb = (u16*)(ws + 2 * MB);
    u16* Wvb = (u16*)(ws + 4 * MB);
    u16* Wob = (u16*)(ws + 6 * MB);
    u16* qb  = (u16*)(ws + 8 * MB);      // 8 MB each (bf16 activations)
    u16* kb  = (u16*)(ws + 16 * MB);
    u16* vb  = (u16*)(ws + 24 * MB);
    u16* Qh  = (u16*)(ws + 32 * MB);
    u16* Kh  = (u16*)(ws + 40 * MB);
    u16* Vt  = (u16*)(ws + 48 * MB);
    u16* Ao  = qb;                       // qb dead after proj -> alias

    conv_bf16<<<dim3(2048, 7), 256, 0, stream>>>(Wq, Wk, Wv, Wo, q, k, v,
                                                 Wqb, Wkb, Wvb, Wob, qb, kb, vb);
    proj_gemm_bf16<<<dim3(8, 32, 3), 256, 0, stream>>>(qb, kb, vb, Wqb, Wkb, Wvb,
                                                       bq, bk, bv, Qh, Kh, Vt);
    attn_fwd<<<dim3(16, 2 * NHEAD), 256, 0, stream>>>(Qh, Kh, Vt, Ao);
    out_gemm<<<dim3(8, 32), 256, 0, stream>>>(Ao, Wob, bo, (float*)d_out);
  } else {
    // R8 fallback (40 MB scratch)
    u16* Wqb = (u16*)(ws);
    u16* Wkb = (u16*)(ws + 2 * MB);
    u16* Wvb = (u16*)(ws + 4 * MB);
    u16* Wob = (u16*)(ws + 6 * MB);
    u16* Qh  = (u16*)(ws + 8 * MB);
    u16* Kh  = (u16*)(ws + 16 * MB);
    u16* Vt  = (u16*)(ws + 24 * MB);
    u16* Ao  = (u16*)(ws + 32 * MB);

    conv_w<<<dim3(512, 4), 256, 0, stream>>>(Wq, Wk, Wv, Wo, Wqb, Wkb, Wvb, Wob);
    proj_gemm_f32<<<dim3(8, 32, 3), 256, 0, stream>>>(q, k, v, Wqb, Wkb, Wvb,
                                                      bq, bk, bv, Qh, Kh, Vt);
    attn_fwd<<<dim3(16, 2 * NHEAD), 256, 0, stream>>>(Qh, Kh, Vt, Ao);
    out_gemm<<<dim3(8, 32), 256, 0, stream>>>(Ao, Wob, bo, (float*)d_out);
  }
}